// Round 16
// baseline (1443.724 us; speedup 1.0000x reference)
//
#include <hip/hip_runtime.h>
#include <math.h>

#define BATCH   256
#define SEQ     128
#define DMODEL  384
#define DSTATE  64
#define DINNER  768
#define NHEADS  12
#define HEADDIM 64
#define CONVDIM 896
#define DPROJ   1676
#define N1PAD   1792
#define OUTDIM  60
#define MTOT    (BATCH*SEQ)   // 32768

typedef unsigned short u16;
typedef unsigned int   u32;
typedef short bf16x8 __attribute__((ext_vector_type(8)));
typedef float f32x4 __attribute__((ext_vector_type(4)));

#define ASG __attribute__((address_space(1)))
#define ASL __attribute__((address_space(3)))

__device__ __forceinline__ float siluf(float x){ return __fdividef(x, 1.f + __expf(-x)); }
__device__ __forceinline__ float softplusf(float x){ return fmaxf(x,0.f) + log1pf(expf(-fabsf(x))); }
__device__ __forceinline__ u16 f2bf(float x){
  union { float f; unsigned int u; } c; c.f = x;
  unsigned int r = c.u + 0x7FFFu + ((c.u >> 16) & 1u);
  return (u16)(r >> 16);
}
__device__ __forceinline__ float bf2f(u16 u){
  union { unsigned int u; float f; } c; c.u = ((unsigned int)u) << 16;
  return c.f;
}

// x = emb + positional encoding
__global__ void add_pe_kernel(const float* __restrict__ emb, float* __restrict__ x){
  int idx = blockIdx.x*256 + threadIdx.x;
  int d = idx % DMODEL;
  int l = (idx / DMODEL) % SEQ;
  int i = d >> 1;
  float div = expf((float)(2*i) * (-9.210340371976184f/384.f));
  float arg = (float)l * div;
  float pe = (d & 1) ? cosf(arg) : sinf(arg);
  x[idx] = emb[idx] + pe;
}

// weight conversions (per layer, each call)
__global__ void wconv_in2_kernel(const float* __restrict__ w, u16* __restrict__ o){
  int idx = blockIdx.x*256 + threadIdx.x;       // N1PAD*DMODEL total
  int n = idx / DMODEL, k = idx % DMODEL;
  o[idx] = (n < DPROJ) ? f2bf(w[(size_t)n*DMODEL + k]) : (u16)0;
}
__global__ void wconv_out_kernel(const float* __restrict__ w, u16* __restrict__ o){
  int idx = blockIdx.x*256 + threadIdx.x;       // 384*768 total
  o[idx] = f2bf(w[idx]);
}

// xbf = bf16( LN(x)*lnw + lnb ), one wave per row
__global__ void __launch_bounds__(256) ln_bf_kernel(const float* __restrict__ x,
    const float* __restrict__ lnw, const float* __restrict__ lnb, u16* __restrict__ xbf){
  int wave = threadIdx.x >> 6, lane = threadIdx.x & 63;
  int m = blockIdx.x*4 + wave;
  const float* row = x + (size_t)m*DMODEL;
  float v[6], s=0.f, s2=0.f;
  #pragma unroll
  for (int j=0;j<6;j++){ v[j] = row[lane + 64*j]; s += v[j]; s2 += v[j]*v[j]; }
  #pragma unroll
  for (int off=32;off;off>>=1){ s += __shfl_xor(s,off,64); s2 += __shfl_xor(s2,off,64); }
  float m1 = s * (1.f/384.f);
  float var = s2 * (1.f/384.f) - m1*m1;
  float rstd = rsqrtf(var + 1e-5f);
  u16* orow = xbf + (size_t)m*DMODEL;
  #pragma unroll
  for (int j=0;j<6;j++){
    int d = lane + 64*j;
    orow[d] = f2bf((v[j]-m1)*rstd*lnw[d] + lnb[d]);
  }
}

// bf16 MFMA GEMM: 256x128 tile, BK=32, 2-buffer pipeline (R9 schedule:
// stage(t+1) -> compute(t) -> barrier). 4 waves, wave-tile 128x64:
// 12 ds_read_b128 feed 32 MFMA per step (0.375 reads/MFMA).
// __launch_bounds__(256,1): ~190 VGPR budget so acc[8][4] stays in registers
// (R14's (256) default capped at 96 VGPR -> acc spilled to scratch -> 3 GB
// of HBM spill traffic; FETCH/WRITE counters confirmed).
// MODE 0: in-proj epilogue (split z/xBCraw/dt);  MODE 1: out-proj (+= residual f32)
template<int MODE>
__global__ void __launch_bounds__(256, 1) gemm_bf16(
    const u16* __restrict__ A, const u16* __restrict__ W, const int K,
    u16* __restrict__ zo, u16* __restrict__ xbcro, float* __restrict__ dto,
    const float* __restrict__ dt_bias, float* __restrict__ xres)
{
  __shared__ __align__(16) u16 As[2*256*32];   // 32 KB
  __shared__ __align__(16) u16 Bs[2*128*32];   // 16 KB
  const int tid = threadIdx.x;
  const int l = tid & 63;
  const int wv = tid >> 6;
  const int wm = wv >> 1, wn = wv & 1;

  int bx = blockIdx.x, by = blockIdx.y;
  {
    const int nwg = gridDim.x * gridDim.y;
    if ((nwg & 7) == 0){
      const int id  = by * gridDim.x + bx;
      const int nid = (id & 7) * (nwg >> 3) + (id >> 3);
      bx = nid % gridDim.x;
      by = nid / gridDim.x;
    }
  }
  const int m0 = by * 256, n0 = bx * 128;

  f32x4 acc[8][4];
  #pragma unroll
  for (int i=0;i<8;i++)
    #pragma unroll
    for (int j=0;j<4;j++)
      acc[i][j] = (f32x4){0.f,0.f,0.f,0.f};

  const int grow = tid >> 2;            // 0..63
  const int gcol = (tid & 3) * 8;       // 0,8,16,24
  const u16* Abase = A + (size_t)(m0 + grow)*K + gcol;
  const u16* Wbase = W + (size_t)(n0 + grow)*K + gcol;
  const int lb = wv * 512;              // wave-uniform LDS base (lane*16B added by HW)

  auto stage = [&](int buf, int k0){
    #pragma unroll
    for (int it=0; it<4; it++)
      __builtin_amdgcn_global_load_lds((const ASG void*)(Abase + (size_t)it*64*K + k0),
                                       (ASL void*)(&As[buf*8192 + it*2048 + lb]), 16, 0, 0);
    #pragma unroll
    for (int it=0; it<2; it++)
      __builtin_amdgcn_global_load_lds((const ASG void*)(Wbase + (size_t)it*64*K + k0),
                                       (ASL void*)(&Bs[buf*4096 + it*2048 + lb]), 16, 0, 0);
  };

  const int nt = K >> 5;                // 12 (in-proj) / 24 (out-proj)
  stage(0, 0);
  __syncthreads();
  const int rr = l & 15;
  const int ko = (l >> 4) << 3;
  for (int t = 0; t < nt; t++){
    if (t + 1 < nt) stage((t+1)&1, (t+1) << 5);
    const u16* Ac = &As[(t&1)*8192];
    const u16* Bc = &Bs[(t&1)*4096];
    bf16x8 bfv[4];
    #pragma unroll
    for (int fj=0; fj<4; fj++)
      bfv[fj] = *(const bf16x8*)&Bc[(wn*64 + fj*16 + rr)*32 + ko];
    #pragma unroll
    for (int fi=0; fi<8; fi++){
      bf16x8 af = *(const bf16x8*)&Ac[(wm*128 + fi*16 + rr)*32 + ko];
      #pragma unroll
      for (int fj=0; fj<4; fj++)
        acc[fi][fj] = __builtin_amdgcn_mfma_f32_16x16x32_bf16(af, bfv[fj], acc[fi][fj], 0, 0, 0);
    }
    __syncthreads();                    // drains vmcnt(0): prefetched tile landed; buf t reads done
  }

  const int cg = l & 15;
  const int rb = (l >> 4) * 4;
  #pragma unroll
  for (int fi=0; fi<8; fi++){
    #pragma unroll
    for (int r=0; r<4; r++){
      const int m = m0 + wm*128 + fi*16 + rb + r;
      #pragma unroll
      for (int fj=0; fj<4; fj++){
        const int n = n0 + wn*64 + fj*16 + cg;
        float v = acc[fi][fj][r];
        if (MODE == 0){
          if (n < DINNER)            zo[(size_t)m*DINNER + n] = f2bf(v);
          else if (n < DINNER+CONVDIM) xbcro[(size_t)m*CONVDIM + n - DINNER] = f2bf(v);
          else if (n < DPROJ)        dto[(size_t)m*NHEADS + n - (DINNER+CONVDIM)] =
                                        softplusf(v + dt_bias[n - (DINNER+CONVDIM)]);
        } else {
          xres[(size_t)m*DMODEL + n] += v;
        }
      }
    }
  }
}

// conv+SiLU for the shared B/C channels only (computed ONCE, not per head).
__global__ void __launch_bounds__(256) conv_bc_kernel(
    const u16* __restrict__ xbcr, const float* __restrict__ cw,
    const float* __restrict__ cb, u16* __restrict__ xbcc)
{
  int idx = blockIdx.x*256 + threadIdx.x;      // Mc*16 total
  int row = idx >> 4;
  int c8  = (idx & 15) * 8;                    // 0..120 within B|C block
  int lq  = row & (SEQ-1);
  const u16* src = xbcr + (size_t)row*CONVDIM + DINNER + c8;
  bf16x8 tap[4];
  #pragma unroll
  for (int k=0;k<4;k++){
    int d = k - 3;
    if (lq + d >= 0) tap[k] = *(const bf16x8*)(src + (long)d*CONVDIM);
    else             tap[k] = (bf16x8){0,0,0,0,0,0,0,0};
  }
  bf16x8 o;
  #pragma unroll
  for (int j=0;j<8;j++){
    const float4 wv = *(const float4*)&cw[(DINNER + c8 + j)*4];
    float a = cb[DINNER + c8 + j]
            + bf2f((u16)tap[0][j])*wv.x + bf2f((u16)tap[1][j])*wv.y
            + bf2f((u16)tap[2][j])*wv.z + bf2f((u16)tap[3][j])*wv.w;
    o[j] = (short)f2bf(siluf(a));
  }
  *(bf16x8*)&xbcc[(size_t)row*128 + c8] = o;
}

// SSD (Mamba2 matrix form), one block per (batch, head).
// LDS XOR-swizzled (byte ^= (row&7)<<4). B/C pre-conv'd (xbcc); X conv fused.
__global__ void __launch_bounds__(256) ssd_kernel(
  const u16* __restrict__ xbcr, const u16* __restrict__ xbcc,
  const float* __restrict__ dtb,
  const float* __restrict__ cw, const float* __restrict__ cb,
  const float* __restrict__ A_log, const float* __restrict__ Dp,
  u16* __restrict__ y)
{
  const int b = blockIdx.x, h = blockIdx.y;
  const int tid = threadIdx.x;
  const int l = tid & 63;
  const int w = tid >> 6;
  const float A  = -__expf(A_log[h]);
  const float Dh = Dp[h];

  __shared__ __align__(16) u16 cbm[128*128];   // C[128][64]@0 | B[128][64]@16K; M[128][128] reuses
  __shared__ __align__(16) u16 XtS[64*128];    // Xt[p][s]
  __shared__ float cum[128];
  __shared__ float dts[128];
  char* Cb = (char*)cbm;
  char* Bb = (char*)cbm + 16384;
  char* Mb = (char*)cbm;
  char* Xb = (char*)XtS;

  const u16* xrow  = xbcr + (size_t)b*SEQ*CONVDIM;
  const u16* ccrow = xbcc + (size_t)b*SEQ*128;

  // wave 0: dt loads + shuffle-based inclusive cumsum of dt*A (no barriers)
  if (w == 0){
    float a0 = dtb[((size_t)b*SEQ + 2*l)*NHEADS + h];
    float a1 = dtb[((size_t)b*SEQ + 2*l+1)*NHEADS + h];
    float ps = (a0 + a1) * A;
    #pragma unroll
    for (int off=1; off<64; off<<=1){
      float v = __shfl_up(ps, off, 64);
      if (l >= off) ps += v;
    }
    float excl = ps - (a0 + a1)*A;
    cum[2*l]   = excl + a0*A;
    cum[2*l+1] = ps;
    dts[2*l]   = a0;
    dts[2*l+1] = a1;
  }

  // stage conv'd B/C: plain b128 copy into swizzled LDS
  {
    const int row0 = tid >> 4;          // 0..15
    const int colc = (tid & 15) * 8;    // 0..120
    #pragma unroll
    for (int it=0; it<8; it++){
      const int r = row0 + 16*it;
      bf16x8 v = *(const bf16x8*)&ccrow[(size_t)r*128 + colc];
      if (colc < 64) *(bf16x8*)(Bb + ((r*128 + 2*colc)      ^ ((r&7)<<4))) = v;
      else           *(bf16x8*)(Cb + ((r*128 + 2*(colc-64)) ^ ((r&7)<<4))) = v;
    }
  }

  // stage X transposed with rolling conv: wave w owns s in [32w,32w+32), lane = p
  {
    const int cx = h*HEADDIM + l;
    const float4 cwx = *(const float4*)&cw[cx*4];
    const float cbx = cb[cx];
    const int sb = 32*w;
    float p3=0.f, p2=0.f, p1=0.f;
    if (w > 0){
      p3 = bf2f(xrow[(size_t)(sb-3)*CONVDIM + cx]);
      p2 = bf2f(xrow[(size_t)(sb-2)*CONVDIM + cx]);
      p1 = bf2f(xrow[(size_t)(sb-1)*CONVDIM + cx]);
    }
    #pragma unroll
    for (int it=0; it<16; it++){
      const int s = sb + 2*it;
      const float r0 = bf2f(xrow[(size_t)s*CONVDIM + cx]);
      const float r1 = bf2f(xrow[(size_t)(s+1)*CONVDIM + cx]);
      const float v0 = siluf(cbx + p3*cwx.x + p2*cwx.y + p1*cwx.z + r0*cwx.w);
      const float v1 = siluf(cbx + p2*cwx.x + p1*cwx.y + r0*cwx.z + r1*cwx.w);
      const u32 pk = (u32)f2bf(v0) | ((u32)f2bf(v1) << 16);
      *(u32*)(Xb + ((l*256 + 2*s) ^ ((l&7)<<4))) = pk;
      p3 = p1; p2 = r0; p1 = r1;
    }
  }
  __syncthreads();

  // ---- G = C · B^T : wave w -> rows [32w,32w+32) x 128 cols ----
  const int t0 = w*32;
  const int rr = l & 15;
  const int kg = (l >> 4) << 3;
  f32x4 g[2][8];
  #pragma unroll
  for (int i=0;i<2;i++)
    #pragma unroll
    for (int j=0;j<8;j++)
      g[i][j] = (f32x4){0.f,0.f,0.f,0.f};
  #pragma unroll
  for (int k0=0; k0<64; k0+=32){
    const int ko = k0 + kg;
    bf16x8 af[2], bfv[8];
    #pragma unroll
    for (int fi=0; fi<2; fi++){
      const int r = t0 + 16*fi + rr;
      af[fi] = *(const bf16x8*)(Cb + ((r*128 + 2*ko) ^ ((r&7)<<4)));
    }
    #pragma unroll
    for (int fj=0; fj<8; fj++){
      const int r = 16*fj + rr;
      bfv[fj] = *(const bf16x8*)(Bb + ((r*128 + 2*ko) ^ ((r&7)<<4)));
    }
    #pragma unroll
    for (int fi=0; fi<2; fi++)
      #pragma unroll
      for (int fj=0; fj<8; fj++)
        g[fi][fj] = __builtin_amdgcn_mfma_f32_16x16x32_bf16(af[fi], bfv[fj], g[fi][fj], 0, 0, 0);
  }
  __syncthreads();   // C/B reads done; M may overwrite

  // ---- M[t,s] = mask * exp(cum[t]-cum[s]) * dt[s] * G ----
  {
    const int rowg = (l >> 4) * 4;
    const int colg = l & 15;
    #pragma unroll
    for (int fi=0; fi<2; fi++){
      #pragma unroll
      for (int fj=0; fj<8; fj++){
        const int s = 16*fj + colg;
        const float cs = cum[s];
        const float ds = dts[s];
        #pragma unroll
        for (int r=0; r<4; r++){
          const int t = t0 + 16*fi + rowg + r;
          float m = 0.f;
          if (t >= s) m = __expf(cum[t] - cs) * ds * g[fi][fj][r];
          *(u16*)(Mb + ((t*256 + 2*s) ^ ((t&7)<<4))) = f2bf(m);
        }
      }
    }
  }
  __syncthreads();

  // ---- Y = M · Xt : rows [32w,32w+32) x 64, K = 128 ----
  f32x4 acc[2][4];
  #pragma unroll
  for (int i=0;i<2;i++)
    #pragma unroll
    for (int j=0;j<4;j++)
      acc[i][j] = (f32x4){0.f,0.f,0.f,0.f};
  #pragma unroll
  for (int k0=0; k0<128; k0+=32){
    const int ko = k0 + kg;
    bf16x8 af[2], bfv[4];
    #pragma unroll
    for (int fi=0; fi<2; fi++){
      const int r = t0 + 16*fi + rr;
      af[fi] = *(const bf16x8*)(Mb + ((r*256 + 2*ko) ^ ((r&7)<<4)));
    }
    #pragma unroll
    for (int fj=0; fj<4; fj++){
      const int r = 16*fj + rr;
      bfv[fj] = *(const bf16x8*)(Xb + ((r*256 + 2*ko) ^ ((r&7)<<4)));
    }
    #pragma unroll
    for (int fi=0; fi<2; fi++)
      #pragma unroll
      for (int fj=0; fj<4; fj++)
        acc[fi][fj] = __builtin_amdgcn_mfma_f32_16x16x32_bf16(af[fi], bfv[fj], acc[fi][fj], 0, 0, 0);
  }

  // ---- epilogue: y = Y + D*x (conv'd x from swizzled XtS) ----
  {
    const int rowg = (l >> 4) * 4;
    const int colg = l & 15;
    u16* yb = y + (size_t)b*SEQ*DINNER + h*HEADDIM;
    #pragma unroll
    for (int fi=0; fi<2; fi++){
      #pragma unroll
      for (int r=0; r<4; r++){
        const int t = t0 + 16*fi + rowg + r;
        #pragma unroll
        for (int fj=0; fj<4; fj++){
          const int p = 16*fj + colg;
          const float xval = bf2f(*(const u16*)(Xb + ((p*256 + 2*t) ^ ((p&7)<<4))));
          yb[(size_t)t*DINNER + p] = f2bf(acc[fi][fj][r] + Dh*xval);
        }
      }
    }
  }
}

// g = y * silu(z); g *= rsqrt(mean(g^2)+eps) * norm_w  (bf16 in-place in y)
// 192 threads/row, 4 bf16 per thread via uint2 (8B) loads/stores.
__global__ void __launch_bounds__(192) gate_rms_bf_kernel(const u16* __restrict__ z,
    const float* __restrict__ normw, u16* __restrict__ y){
  const int m = blockIdx.x, tid = threadIdx.x;
  const uint2 zz = *(const uint2*)(z + (size_t)m*DINNER + tid*4);
  const uint2 yy = *(const uint2*)(y + (size_t)m*DINNER + tid*4);
  float gv[4];
  gv[0] = bf2f((u16)(yy.x & 0xffff)) * siluf(bf2f((u16)(zz.x & 0xffff)));
  gv[1] = bf2f((u16)(yy.x >> 16))    * siluf(bf2f((u16)(zz.x >> 16)));
  gv[2] = bf2f((u16)(yy.y & 0xffff)) * siluf(bf2f((u16)(zz.y & 0xffff)));
  gv[3] = bf2f((u16)(yy.y >> 16))    * siluf(bf2f((u16)(zz.y >> 16)));
  float ss = gv[0]*gv[0] + gv[1]*gv[1] + gv[2]*gv[2] + gv[3]*gv[3];
  #pragma unroll
  for (int off=32;off;off>>=1) ss += __shfl_xor(ss,off,64);
  __shared__ float red[3];
  if ((tid&63)==0) red[tid>>6] = ss;
  __syncthreads();
  const float rms = rsqrtf((red[0]+red[1]+red[2])*(1.f/768.f) + 1e-5f);
  const float4 nw = *(const float4*)(normw + tid*4);
  u32 o0 = (u32)f2bf(gv[0]*rms*nw.x) | ((u32)f2bf(gv[1]*rms*nw.y) << 16);
  u32 o1 = (u32)f2bf(gv[2]*rms*nw.z) | ((u32)f2bf(gv[3]*rms*nw.w) << 16);
  *(uint2*)(y + (size_t)m*DINNER + tid*4) = make_uint2(o0, o1);
}

// final LN on last timestep + 60x384 projection (f32)
__global__ void __launch_bounds__(64) final_kernel(const float* __restrict__ x,
  const float* __restrict__ onw, const float* __restrict__ onb,
  const float* __restrict__ pw, const float* __restrict__ pb, float* __restrict__ out)
{
  int b = blockIdx.x;
  int lane = threadIdx.x;
  const float* row = x + ((size_t)b*SEQ + (SEQ-1))*DMODEL;
  float s=0.f, s2=0.f;
  float v[6];
  #pragma unroll
  for (int j=0;j<6;j++){ v[j] = row[lane + 64*j]; s += v[j]; s2 += v[j]*v[j]; }
  #pragma unroll
  for (int off=32;off;off>>=1){ s += __shfl_xor(s,off,64); s2 += __shfl_xor(s2,off,64); }
  float m1 = s*(1.f/384.f);
  float var = s2*(1.f/384.f) - m1*m1;
  float rstd = rsqrtf(var + 1e-5f);
  __shared__ float xn[384];
  #pragma unroll
  for (int j=0;j<6;j++){
    int d = lane + 64*j;
    xn[d] = (v[j]-m1)*rstd*onw[d] + onb[d];
  }
  __syncthreads();
  if (lane < OUTDIM){
    const float* wrow = pw + lane*DMODEL;
    float acc = pb[lane];
    #pragma unroll 4
    for (int d=0; d<DMODEL; d+=4){
      float4 xv = *(const float4*)&xn[d];
      float4 wv = *(const float4*)&wrow[d];
      acc += xv.x*wv.x + xv.y*wv.y + xv.z*wv.z + xv.w*wv.w;
    }
    out[b*OUTDIM + lane] = acc;
  }
}

extern "C" void kernel_launch(void* const* d_in, const int* in_sizes, int n_in,
                              void* d_out, int out_size, void* d_ws, size_t ws_size,
                              hipStream_t stream){
  const float* emb        = (const float*)d_in[0];
  const float* in_proj_w  = (const float*)d_in[1];
  const float* conv_w     = (const float*)d_in[2];
  const float* conv_b     = (const float*)d_in[3];
  const float* dt_bias    = (const float*)d_in[4];
  const float* A_log      = (const float*)d_in[5];
  const float* Dp         = (const float*)d_in[6];
  const float* mnw        = (const float*)d_in[7];
  const float* out_proj_w = (const float*)d_in[8];
  const float* ln_w       = (const float*)d_in[9];
  const float* ln_b       = (const float*)d_in[10];
  const float* onw        = (const float*)d_in[11];
  const float* onb        = (const float*)d_in[12];
  const float* pw         = (const float*)d_in[13];
  const float* pb         = (const float*)d_in[14];
  float* out = (float*)d_out;

  // ---- adaptive workspace ----
  const size_t XB    = (size_t)MTOT*DMODEL*4;
  const size_t XBFB  = (size_t)MTOT*DMODEL*2;
  const size_t WINB  = (size_t)N1PAD*DMODEL*2;
  const size_t WOUTB = (size_t)DMODEL*DINNER*2;
  const size_t fixed = XB + XBFB + WINB + WOUTB;
  int CB = 256;
  while (CB > 2 && fixed + (size_t)CB*SEQ*5168ull > ws_size) CB >>= 1;
  const int Mc = CB*SEQ;
  const int nchunks = BATCH / CB;

  char* p = (char*)d_ws;
  float* x      = (float*)p;  p += XB;
  u16*   xbf    = (u16*)p;    p += XBFB;
  u16*   wbfin  = (u16*)p;    p += WINB;
  u16*   wbfout = (u16*)p;    p += WOUTB;
  u16*   z      = (u16*)p;    p += (size_t)Mc*DINNER*2;
  u16*   xbcr   = (u16*)p;    p += (size_t)Mc*CONVDIM*2;
  u16*   xbcc   = (u16*)p;    p += (size_t)Mc*128*2;
  float* dt     = (float*)p;  p += (size_t)Mc*NHEADS*4;
  u16*   y      = (u16*)p;

  add_pe_kernel<<<MTOT*DMODEL/256,256,0,stream>>>(emb, x);
  for (int i=0;i<2;i++){
    wconv_in2_kernel<<<N1PAD*DMODEL/256,256,0,stream>>>(in_proj_w + (size_t)i*DPROJ*DMODEL, wbfin);
    wconv_out_kernel<<<DMODEL*DINNER/256,256,0,stream>>>(out_proj_w + (size_t)i*DMODEL*DINNER, wbfout);
    ln_bf_kernel<<<MTOT/4,256,0,stream>>>(x, ln_w + (size_t)i*DMODEL, ln_b + (size_t)i*DMODEL, xbf);
    for (int c=0;c<nchunks;c++){
      const u16* ac = xbf + (size_t)c*Mc*DMODEL;
      float*     xc = x   + (size_t)c*Mc*DMODEL;
      dim3 g1(N1PAD/128, Mc/256);
      gemm_bf16<0><<<g1,256,0,stream>>>(ac, wbfin, DMODEL, z, xbcr, dt,
                                        dt_bias + (size_t)i*NHEADS, nullptr);
      conv_bc_kernel<<<Mc/16,256,0,stream>>>(xbcr, conv_w + (size_t)i*CONVDIM*4,
                                             conv_b + (size_t)i*CONVDIM, xbcc);
      dim3 gs(CB, NHEADS);
      ssd_kernel<<<gs,256,0,stream>>>(xbcr, xbcc, dt,
          conv_w + (size_t)i*CONVDIM*4, conv_b + (size_t)i*CONVDIM,
          A_log + (size_t)i*NHEADS, Dp + (size_t)i*NHEADS, y);
      gate_rms_bf_kernel<<<Mc,192,0,stream>>>(z, mnw + (size_t)i*DINNER, y);
      dim3 g2(DMODEL/128, Mc/256);
      gemm_bf16<1><<<g2,256,0,stream>>>(y, wbfout, DINNER, nullptr, nullptr, nullptr, nullptr, xc);
    }
  }
  final_kernel<<<BATCH,64,0,stream>>>(x, onw, onb, pw, pb, out);
}

// Round 17
// 543.190 us; speedup vs baseline: 2.6579x; 2.6579x over previous
//
#include <hip/hip_runtime.h>
#include <math.h>

#define BATCH   256
#define SEQ     128
#define DMODEL  384
#define DSTATE  64
#define DINNER  768
#define NHEADS  12
#define HEADDIM 64
#define CONVDIM 896
#define DPROJ   1676
#define N1PAD   1792
#define OUTDIM  60
#define MTOT    (BATCH*SEQ)   // 32768

typedef unsigned short u16;
typedef unsigned int   u32;
typedef short bf16x8 __attribute__((ext_vector_type(8)));
typedef float f32x4 __attribute__((ext_vector_type(4)));

#define ASG __attribute__((address_space(1)))
#define ASL __attribute__((address_space(3)))

__device__ __forceinline__ float siluf(float x){ return __fdividef(x, 1.f + __expf(-x)); }
__device__ __forceinline__ float softplusf(float x){ return fmaxf(x,0.f) + log1pf(expf(-fabsf(x))); }
__device__ __forceinline__ u16 f2bf(float x){
  union { float f; unsigned int u; } c; c.f = x;
  unsigned int r = c.u + 0x7FFFu + ((c.u >> 16) & 1u);
  return (u16)(r >> 16);
}
__device__ __forceinline__ float bf2f(u16 u){
  union { unsigned int u; float f; } c; c.u = ((unsigned int)u) << 16;
  return c.f;
}

// weight conversions (per layer, each call)
__global__ void wconv_in2_kernel(const float* __restrict__ w, u16* __restrict__ o){
  int idx = blockIdx.x*256 + threadIdx.x;       // N1PAD*DMODEL total
  int n = idx / DMODEL, k = idx % DMODEL;
  o[idx] = (n < DPROJ) ? f2bf(w[(size_t)n*DMODEL + k]) : (u16)0;
}
__global__ void wconv_out_kernel(const float* __restrict__ w, u16* __restrict__ o){
  int idx = blockIdx.x*256 + threadIdx.x;       // 384*768 total
  o[idx] = f2bf(w[idx]);
}

// xbf = bf16( LN(in)*lnw + lnb ), one wave per row.
// FUSE_PE=1 (layer 0): in = emb, v[j] = emb + positional encoding (computed
// inline, same fp32 recipe as the old add_pe_kernel); also writes x for the
// residual stream. Saves the separate add_pe dispatch + a 50 MB x re-read.
template<int FUSE_PE>
__global__ void __launch_bounds__(256) ln_bf_kernel(const float* __restrict__ in,
    const float* __restrict__ lnw, const float* __restrict__ lnb,
    u16* __restrict__ xbf, float* __restrict__ xout){
  int wave = threadIdx.x >> 6, lane = threadIdx.x & 63;
  int m = blockIdx.x*4 + wave;
  const float* row = in + (size_t)m*DMODEL;
  float v[6], s=0.f, s2=0.f;
  #pragma unroll
  for (int j=0;j<6;j++){
    int d = lane + 64*j;
    float val = row[d];
    if (FUSE_PE){
      int l = m & (SEQ-1);
      int i = d >> 1;
      float div = expf((float)(2*i) * (-9.210340371976184f/384.f));
      float arg = (float)l * div;
      val += (d & 1) ? cosf(arg) : sinf(arg);
    }
    v[j] = val; s += val; s2 += val*val;
  }
  #pragma unroll
  for (int off=32;off;off>>=1){ s += __shfl_xor(s,off,64); s2 += __shfl_xor(s2,off,64); }
  float m1 = s * (1.f/384.f);
  float var = s2 * (1.f/384.f) - m1*m1;
  float rstd = rsqrtf(var + 1e-5f);
  u16* orow = xbf + (size_t)m*DMODEL;
  float* xrow = FUSE_PE ? (xout + (size_t)m*DMODEL) : nullptr;
  #pragma unroll
  for (int j=0;j<6;j++){
    int d = lane + 64*j;
    if (FUSE_PE) xrow[d] = v[j];
    orow[d] = f2bf((v[j]-m1)*rstd*lnw[d] + lnb[d]);
  }
}

// bf16 MFMA GEMM: 128x128 tile, BK=32, 2-buffer pipeline with COUNTED vmcnt.
// iter t: stage(t+1) -> vmcnt(4) [stage t landed, t+1 in flight] -> s_barrier
//         -> ds_read+MFMA(t) -> lgkmcnt(0) -> s_barrier.  (R11, measured best)
// MODE 0: in-proj epilogue (split z/xBCraw/dt);  MODE 1: out-proj (+= residual f32)
template<int MODE>
__global__ void __launch_bounds__(256) gemm_bf16(
    const u16* __restrict__ A, const u16* __restrict__ W, const int K,
    u16* __restrict__ zo, u16* __restrict__ xbcro, float* __restrict__ dto,
    const float* __restrict__ dt_bias, float* __restrict__ xres)
{
  __shared__ __align__(16) u16 As[2*128*32];   // 16 KB
  __shared__ __align__(16) u16 Bs[2*128*32];   // 16 KB
  const int tid = threadIdx.x;
  const int l = tid & 63;
  const int w = tid >> 6;
  const int wm = w >> 1, wn = w & 1;

  int bx = blockIdx.x, by = blockIdx.y;
  {
    const int nwg = gridDim.x * gridDim.y;
    if ((nwg & 7) == 0){
      const int id  = by * gridDim.x + bx;
      const int nid = (id & 7) * (nwg >> 3) + (id >> 3);
      bx = nid % gridDim.x;
      by = nid / gridDim.x;
    }
  }
  const int m0 = by * 128, n0 = bx * 128;

  f32x4 acc[4][4];
  #pragma unroll
  for (int i=0;i<4;i++)
    #pragma unroll
    for (int j=0;j<4;j++)
      acc[i][j] = (f32x4){0.f,0.f,0.f,0.f};

  const int grow = tid >> 2;            // 0..63
  const int gcol = (tid & 3) * 8;       // 0,8,16,24
  const u16* Abase = A + (size_t)(m0 + grow)*K + gcol;
  const u16* Wbase = W + (size_t)(n0 + grow)*K + gcol;
  const int lb = w*512;

  auto stage = [&](int buf, int k0){
    #pragma unroll
    for (int it=0; it<2; it++){
      __builtin_amdgcn_global_load_lds((const ASG void*)(Abase + (size_t)it*64*K + k0),
                                       (ASL void*)(&As[buf*4096 + it*2048 + lb]), 16, 0, 0);
      __builtin_amdgcn_global_load_lds((const ASG void*)(Wbase + (size_t)it*64*K + k0),
                                       (ASL void*)(&Bs[buf*4096 + it*2048 + lb]), 16, 0, 0);
    }
  };

  const int nt = K >> 5;                // 12 (in-proj) / 24 (out-proj)
  stage(0, 0);
  const int rr = l & 15;
  const int ko = (l >> 4) << 3;
  for (int t = 0; t < nt; t++){
    if (t + 1 < nt){
      stage((t+1)&1, (t+1)<<5);
      asm volatile("s_waitcnt vmcnt(4)" ::: "memory");   // stage(t) landed
    } else {
      asm volatile("s_waitcnt vmcnt(0)" ::: "memory");
    }
    __builtin_amdgcn_s_barrier();
    __builtin_amdgcn_sched_barrier(0);
    const u16* Ac = &As[(t&1)*4096];
    const u16* Bc = &Bs[(t&1)*4096];
    bf16x8 af[4], bfv[4];
    #pragma unroll
    for (int f=0; f<4; f++){
      af[f]  = *(const bf16x8*)&Ac[(wm*64 + f*16 + rr)*32 + ko];
      bfv[f] = *(const bf16x8*)&Bc[(wn*64 + f*16 + rr)*32 + ko];
    }
    #pragma unroll
    for (int fi=0; fi<4; fi++)
      #pragma unroll
      for (int fj=0; fj<4; fj++)
        acc[fi][fj] = __builtin_amdgcn_mfma_f32_16x16x32_bf16(af[fi], bfv[fj], acc[fi][fj], 0, 0, 0);
    asm volatile("s_waitcnt lgkmcnt(0)" ::: "memory");   // LDS reads done
    __builtin_amdgcn_sched_barrier(0);
    __builtin_amdgcn_s_barrier();                        // safe to overwrite buf
  }

  const int cg = l & 15;
  const int rb = (l >> 4) * 4;
  #pragma unroll
  for (int fi=0; fi<4; fi++){
    #pragma unroll
    for (int r=0; r<4; r++){
      const int m = m0 + wm*64 + fi*16 + rb + r;
      #pragma unroll
      for (int fj=0; fj<4; fj++){
        const int n = n0 + wn*64 + fj*16 + cg;
        float v = acc[fi][fj][r];
        if (MODE == 0){
          if (n < DINNER)            zo[(size_t)m*DINNER + n] = f2bf(v);
          else if (n < DINNER+CONVDIM) xbcro[(size_t)m*CONVDIM + n - DINNER] = f2bf(v);
          else if (n < DPROJ)        dto[(size_t)m*NHEADS + n - (DINNER+CONVDIM)] =
                                        softplusf(v + dt_bias[n - (DINNER+CONVDIM)]);
        } else {
          xres[(size_t)m*DMODEL + n] += v;
        }
      }
    }
  }
}

// conv+SiLU for the shared B/C channels only (computed ONCE, not per head).
__global__ void __launch_bounds__(256) conv_bc_kernel(
    const u16* __restrict__ xbcr, const float* __restrict__ cw,
    const float* __restrict__ cb, u16* __restrict__ xbcc)
{
  int idx = blockIdx.x*256 + threadIdx.x;      // Mc*16 total
  int row = idx >> 4;
  int c8  = (idx & 15) * 8;                    // 0..120 within B|C block
  int lq  = row & (SEQ-1);
  const u16* src = xbcr + (size_t)row*CONVDIM + DINNER + c8;
  bf16x8 tap[4];
  #pragma unroll
  for (int k=0;k<4;k++){
    int d = k - 3;
    if (lq + d >= 0) tap[k] = *(const bf16x8*)(src + (long)d*CONVDIM);
    else             tap[k] = (bf16x8){0,0,0,0,0,0,0,0};
  }
  bf16x8 o;
  #pragma unroll
  for (int j=0;j<8;j++){
    const float4 wv = *(const float4*)&cw[(DINNER + c8 + j)*4];
    float a = cb[DINNER + c8 + j]
            + bf2f((u16)tap[0][j])*wv.x + bf2f((u16)tap[1][j])*wv.y
            + bf2f((u16)tap[2][j])*wv.z + bf2f((u16)tap[3][j])*wv.w;
    o[j] = (short)f2bf(siluf(a));
  }
  *(bf16x8*)&xbcc[(size_t)row*128 + c8] = o;
}

// SSD (Mamba2 matrix form), one block per (batch, head).
// LDS XOR-swizzled (byte ^= (row&7)<<4). B/C pre-conv'd (xbcc); X conv fused.
__global__ void __launch_bounds__(256) ssd_kernel(
  const u16* __restrict__ xbcr, const u16* __restrict__ xbcc,
  const float* __restrict__ dtb,
  const float* __restrict__ cw, const float* __restrict__ cb,
  const float* __restrict__ A_log, const float* __restrict__ Dp,
  u16* __restrict__ y)
{
  const int b = blockIdx.x, h = blockIdx.y;
  const int tid = threadIdx.x;
  const int l = tid & 63;
  const int w = tid >> 6;
  const float A  = -__expf(A_log[h]);
  const float Dh = Dp[h];

  __shared__ __align__(16) u16 cbm[128*128];   // C[128][64]@0 | B[128][64]@16K; M[128][128] reuses
  __shared__ __align__(16) u16 XtS[64*128];    // Xt[p][s]
  __shared__ float cum[128];
  __shared__ float dts[128];
  char* Cb = (char*)cbm;
  char* Bb = (char*)cbm + 16384;
  char* Mb = (char*)cbm;
  char* Xb = (char*)XtS;

  const u16* xrow  = xbcr + (size_t)b*SEQ*CONVDIM;
  const u16* ccrow = xbcc + (size_t)b*SEQ*128;

  // wave 0: dt loads + shuffle-based inclusive cumsum of dt*A (no barriers)
  if (w == 0){
    float a0 = dtb[((size_t)b*SEQ + 2*l)*NHEADS + h];
    float a1 = dtb[((size_t)b*SEQ + 2*l+1)*NHEADS + h];
    float ps = (a0 + a1) * A;
    #pragma unroll
    for (int off=1; off<64; off<<=1){
      float v = __shfl_up(ps, off, 64);
      if (l >= off) ps += v;
    }
    float excl = ps - (a0 + a1)*A;
    cum[2*l]   = excl + a0*A;
    cum[2*l+1] = ps;
    dts[2*l]   = a0;
    dts[2*l+1] = a1;
  }

  // stage conv'd B/C: plain b128 copy into swizzled LDS
  {
    const int row0 = tid >> 4;          // 0..15
    const int colc = (tid & 15) * 8;    // 0..120
    #pragma unroll
    for (int it=0; it<8; it++){
      const int r = row0 + 16*it;
      bf16x8 v = *(const bf16x8*)&ccrow[(size_t)r*128 + colc];
      if (colc < 64) *(bf16x8*)(Bb + ((r*128 + 2*colc)      ^ ((r&7)<<4))) = v;
      else           *(bf16x8*)(Cb + ((r*128 + 2*(colc-64)) ^ ((r&7)<<4))) = v;
    }
  }

  // stage X transposed with rolling conv: wave w owns s in [32w,32w+32), lane = p
  {
    const int cx = h*HEADDIM + l;
    const float4 cwx = *(const float4*)&cw[cx*4];
    const float cbx = cb[cx];
    const int sb = 32*w;
    float p3=0.f, p2=0.f, p1=0.f;
    if (w > 0){
      p3 = bf2f(xrow[(size_t)(sb-3)*CONVDIM + cx]);
      p2 = bf2f(xrow[(size_t)(sb-2)*CONVDIM + cx]);
      p1 = bf2f(xrow[(size_t)(sb-1)*CONVDIM + cx]);
    }
    #pragma unroll
    for (int it=0; it<16; it++){
      const int s = sb + 2*it;
      const float r0 = bf2f(xrow[(size_t)s*CONVDIM + cx]);
      const float r1 = bf2f(xrow[(size_t)(s+1)*CONVDIM + cx]);
      const float v0 = siluf(cbx + p3*cwx.x + p2*cwx.y + p1*cwx.z + r0*cwx.w);
      const float v1 = siluf(cbx + p2*cwx.x + p1*cwx.y + r0*cwx.z + r1*cwx.w);
      const u32 pk = (u32)f2bf(v0) | ((u32)f2bf(v1) << 16);
      *(u32*)(Xb + ((l*256 + 2*s) ^ ((l&7)<<4))) = pk;
      p3 = p1; p2 = r0; p1 = r1;
    }
  }
  __syncthreads();

  // ---- G = C · B^T : wave w -> rows [32w,32w+32) x 128 cols ----
  const int t0 = w*32;
  const int rr = l & 15;
  const int kg = (l >> 4) << 3;
  f32x4 g[2][8];
  #pragma unroll
  for (int i=0;i<2;i++)
    #pragma unroll
    for (int j=0;j<8;j++)
      g[i][j] = (f32x4){0.f,0.f,0.f,0.f};
  #pragma unroll
  for (int k0=0; k0<64; k0+=32){
    const int ko = k0 + kg;
    bf16x8 af[2], bfv[8];
    #pragma unroll
    for (int fi=0; fi<2; fi++){
      const int r = t0 + 16*fi + rr;
      af[fi] = *(const bf16x8*)(Cb + ((r*128 + 2*ko) ^ ((r&7)<<4)));
    }
    #pragma unroll
    for (int fj=0; fj<8; fj++){
      const int r = 16*fj + rr;
      bfv[fj] = *(const bf16x8*)(Bb + ((r*128 + 2*ko) ^ ((r&7)<<4)));
    }
    #pragma unroll
    for (int fi=0; fi<2; fi++)
      #pragma unroll
      for (int fj=0; fj<8; fj++)
        g[fi][fj] = __builtin_amdgcn_mfma_f32_16x16x32_bf16(af[fi], bfv[fj], g[fi][fj], 0, 0, 0);
  }
  __syncthreads();   // C/B reads done; M may overwrite

  // ---- M[t,s] = mask * exp(cum[t]-cum[s]) * dt[s] * G ----
  {
    const int rowg = (l >> 4) * 4;
    const int colg = l & 15;
    #pragma unroll
    for (int fi=0; fi<2; fi++){
      #pragma unroll
      for (int fj=0; fj<8; fj++){
        const int s = 16*fj + colg;
        const float cs = cum[s];
        const float ds = dts[s];
        #pragma unroll
        for (int r=0; r<4; r++){
          const int t = t0 + 16*fi + rowg + r;
          float m = 0.f;
          if (t >= s) m = __expf(cum[t] - cs) * ds * g[fi][fj][r];
          *(u16*)(Mb + ((t*256 + 2*s) ^ ((t&7)<<4))) = f2bf(m);
        }
      }
    }
  }
  __syncthreads();

  // ---- Y = M · Xt : rows [32w,32w+32) x 64, K = 128 ----
  f32x4 acc[2][4];
  #pragma unroll
  for (int i=0;i<2;i++)
    #pragma unroll
    for (int j=0;j<4;j++)
      acc[i][j] = (f32x4){0.f,0.f,0.f,0.f};
  #pragma unroll
  for (int k0=0; k0<128; k0+=32){
    const int ko = k0 + kg;
    bf16x8 af[2], bfv[4];
    #pragma unroll
    for (int fi=0; fi<2; fi++){
      const int r = t0 + 16*fi + rr;
      af[fi] = *(const bf16x8*)(Mb + ((r*256 + 2*ko) ^ ((r&7)<<4)));
    }
    #pragma unroll
    for (int fj=0; fj<4; fj++){
      const int r = 16*fj + rr;
      bfv[fj] = *(const bf16x8*)(Xb + ((r*256 + 2*ko) ^ ((r&7)<<4)));
    }
    #pragma unroll
    for (int fi=0; fi<2; fi++)
      #pragma unroll
      for (int fj=0; fj<4; fj++)
        acc[fi][fj] = __builtin_amdgcn_mfma_f32_16x16x32_bf16(af[fi], bfv[fj], acc[fi][fj], 0, 0, 0);
  }

  // ---- epilogue: y = Y + D*x (conv'd x from swizzled XtS) ----
  {
    const int rowg = (l >> 4) * 4;
    const int colg = l & 15;
    u16* yb = y + (size_t)b*SEQ*DINNER + h*HEADDIM;
    #pragma unroll
    for (int fi=0; fi<2; fi++){
      #pragma unroll
      for (int r=0; r<4; r++){
        const int t = t0 + 16*fi + rowg + r;
        #pragma unroll
        for (int fj=0; fj<4; fj++){
          const int p = 16*fj + colg;
          const float xval = bf2f(*(const u16*)(Xb + ((p*256 + 2*t) ^ ((p&7)<<4))));
          yb[(size_t)t*DINNER + p] = f2bf(acc[fi][fj][r] + Dh*xval);
        }
      }
    }
  }
}

// g = y * silu(z); g *= rsqrt(mean(g^2)+eps) * norm_w  (bf16 in-place in y)
// 192 threads/row, 4 bf16 per thread via uint2 (8B) loads/stores.
__global__ void __launch_bounds__(192) gate_rms_bf_kernel(const u16* __restrict__ z,
    const float* __restrict__ normw, u16* __restrict__ y){
  const int m = blockIdx.x, tid = threadIdx.x;
  const uint2 zz = *(const uint2*)(z + (size_t)m*DINNER + tid*4);
  const uint2 yy = *(const uint2*)(y + (size_t)m*DINNER + tid*4);
  float gv[4];
  gv[0] = bf2f((u16)(yy.x & 0xffff)) * siluf(bf2f((u16)(zz.x & 0xffff)));
  gv[1] = bf2f((u16)(yy.x >> 16))    * siluf(bf2f((u16)(zz.x >> 16)));
  gv[2] = bf2f((u16)(yy.y & 0xffff)) * siluf(bf2f((u16)(zz.y & 0xffff)));
  gv[3] = bf2f((u16)(yy.y >> 16))    * siluf(bf2f((u16)(zz.y >> 16)));
  float ss = gv[0]*gv[0] + gv[1]*gv[1] + gv[2]*gv[2] + gv[3]*gv[3];
  #pragma unroll
  for (int off=32;off;off>>=1) ss += __shfl_xor(ss,off,64);
  __shared__ float red[3];
  if ((tid&63)==0) red[tid>>6] = ss;
  __syncthreads();
  const float rms = rsqrtf((red[0]+red[1]+red[2])*(1.f/768.f) + 1e-5f);
  const float4 nw = *(const float4*)(normw + tid*4);
  u32 o0 = (u32)f2bf(gv[0]*rms*nw.x) | ((u32)f2bf(gv[1]*rms*nw.y) << 16);
  u32 o1 = (u32)f2bf(gv[2]*rms*nw.z) | ((u32)f2bf(gv[3]*rms*nw.w) << 16);
  *(uint2*)(y + (size_t)m*DINNER + tid*4) = make_uint2(o0, o1);
}

// final LN on last timestep + 60x384 projection (f32)
__global__ void __launch_bounds__(64) final_kernel(const float* __restrict__ x,
  const float* __restrict__ onw, const float* __restrict__ onb,
  const float* __restrict__ pw, const float* __restrict__ pb, float* __restrict__ out)
{
  int b = blockIdx.x;
  int lane = threadIdx.x;
  const float* row = x + ((size_t)b*SEQ + (SEQ-1))*DMODEL;
  float s=0.f, s2=0.f;
  float v[6];
  #pragma unroll
  for (int j=0;j<6;j++){ v[j] = row[lane + 64*j]; s += v[j]; s2 += v[j]*v[j]; }
  #pragma unroll
  for (int off=32;off;off>>=1){ s += __shfl_xor(s,off,64); s2 += __shfl_xor(s2,off,64); }
  float m1 = s*(1.f/384.f);
  float var = s2*(1.f/384.f) - m1*m1;
  float rstd = rsqrtf(var + 1e-5f);
  __shared__ float xn[384];
  #pragma unroll
  for (int j=0;j<6;j++){
    int d = lane + 64*j;
    xn[d] = (v[j]-m1)*rstd*onw[d] + onb[d];
  }
  __syncthreads();
  if (lane < OUTDIM){
    const float* wrow = pw + lane*DMODEL;
    float acc = pb[lane];
    #pragma unroll 4
    for (int d=0; d<DMODEL; d+=4){
      float4 xv = *(const float4*)&xn[d];
      float4 wv = *(const float4*)&wrow[d];
      acc += xv.x*wv.x + xv.y*wv.y + xv.z*wv.z + xv.w*wv.w;
    }
    out[b*OUTDIM + lane] = acc;
  }
}

extern "C" void kernel_launch(void* const* d_in, const int* in_sizes, int n_in,
                              void* d_out, int out_size, void* d_ws, size_t ws_size,
                              hipStream_t stream){
  const float* emb        = (const float*)d_in[0];
  const float* in_proj_w  = (const float*)d_in[1];
  const float* conv_w     = (const float*)d_in[2];
  const float* conv_b     = (const float*)d_in[3];
  const float* dt_bias    = (const float*)d_in[4];
  const float* A_log      = (const float*)d_in[5];
  const float* Dp         = (const float*)d_in[6];
  const float* mnw        = (const float*)d_in[7];
  const float* out_proj_w = (const float*)d_in[8];
  const float* ln_w       = (const float*)d_in[9];
  const float* ln_b       = (const float*)d_in[10];
  const float* onw        = (const float*)d_in[11];
  const float* onb        = (const float*)d_in[12];
  const float* pw         = (const float*)d_in[13];
  const float* pb         = (const float*)d_in[14];
  float* out = (float*)d_out;

  // ---- adaptive workspace ----
  const size_t XB    = (size_t)MTOT*DMODEL*4;
  const size_t XBFB  = (size_t)MTOT*DMODEL*2;
  const size_t WINB  = (size_t)N1PAD*DMODEL*2;
  const size_t WOUTB = (size_t)DMODEL*DINNER*2;
  const size_t fixed = XB + XBFB + WINB + WOUTB;
  int CB = 256;
  while (CB > 1 && fixed + (size_t)CB*SEQ*5168ull > ws_size) CB >>= 1;
  const int Mc = CB*SEQ;
  const int nchunks = BATCH / CB;

  char* p = (char*)d_ws;
  float* x      = (float*)p;  p += XB;
  u16*   xbf    = (u16*)p;    p += XBFB;
  u16*   wbfin  = (u16*)p;    p += WINB;
  u16*   wbfout = (u16*)p;    p += WOUTB;
  u16*   z      = (u16*)p;    p += (size_t)Mc*DINNER*2;
  u16*   xbcr   = (u16*)p;    p += (size_t)Mc*CONVDIM*2;
  u16*   xbcc   = (u16*)p;    p += (size_t)Mc*128*2;
  float* dt     = (float*)p;  p += (size_t)Mc*NHEADS*4;
  u16*   y      = (u16*)p;

  for (int i=0;i<2;i++){
    wconv_in2_kernel<<<N1PAD*DMODEL/256,256,0,stream>>>(in_proj_w + (size_t)i*DPROJ*DMODEL, wbfin);
    wconv_out_kernel<<<DMODEL*DINNER/256,256,0,stream>>>(out_proj_w + (size_t)i*DMODEL*DINNER, wbfout);
    if (i == 0)
      ln_bf_kernel<1><<<MTOT/4,256,0,stream>>>(emb, ln_w, ln_b, xbf, x);
    else
      ln_bf_kernel<0><<<MTOT/4,256,0,stream>>>(x, ln_w + (size_t)i*DMODEL, ln_b + (size_t)i*DMODEL, xbf, nullptr);
    for (int c=0;c<nchunks;c++){
      const u16* ac = xbf + (size_t)c*Mc*DMODEL;
      float*     xc = x   + (size_t)c*Mc*DMODEL;
      dim3 g1(N1PAD/128, Mc/128);
      gemm_bf16<0><<<g1,256,0,stream>>>(ac, wbfin, DMODEL, z, xbcr, dt,
                                        dt_bias + (size_t)i*NHEADS, nullptr);
      conv_bc_kernel<<<Mc/16,256,0,stream>>>(xbcr, conv_w + (size_t)i*CONVDIM*4,
                                             conv_b + (size_t)i*CONVDIM, xbcc);
      dim3 gs(CB, NHEADS);
      ssd_kernel<<<gs,256,0,stream>>>(xbcr, xbcc, dt,
          conv_w + (size_t)i*CONVDIM*4, conv_b + (size_t)i*CONVDIM,
          A_log + (size_t)i*NHEADS, Dp + (size_t)i*NHEADS, y);
      gate_rms_bf_kernel<<<Mc,192,0,stream>>>(z, mnw + (size_t)i*DINNER, y);
      dim3 g2(DMODEL/128, Mc/128);
      gemm_bf16<1><<<g2,256,0,stream>>>(y, wbfout, DINNER, nullptr, nullptr, nullptr, nullptr, xc);
    }
  }
  final_kernel<<<BATCH,64,0,stream>>>(x, onw, onb, pw, pb, out);
}

// Round 18
// 525.505 us; speedup vs baseline: 2.7473x; 1.0337x over previous
//
#include <hip/hip_runtime.h>
#include <math.h>

#define BATCH   256
#define SEQ     128
#define DMODEL  384
#define DSTATE  64
#define DINNER  768
#define NHEADS  12
#define HEADDIM 64
#define CONVDIM 896
#define DPROJ   1676
#define N1PAD   1792
#define OUTDIM  60
#define MTOT    (BATCH*SEQ)   // 32768

typedef unsigned short u16;
typedef unsigned int   u32;
typedef short bf16x8 __attribute__((ext_vector_type(8)));
typedef float f32x4 __attribute__((ext_vector_type(4)));

#define ASG __attribute__((address_space(1)))
#define ASL __attribute__((address_space(3)))

__device__ __forceinline__ float siluf(float x){ return __fdividef(x, 1.f + __expf(-x)); }
__device__ __forceinline__ float softplusf(float x){ return fmaxf(x,0.f) + log1pf(expf(-fabsf(x))); }
__device__ __forceinline__ u16 f2bf(float x){
  union { float f; unsigned int u; } c; c.f = x;
  unsigned int r = c.u + 0x7FFFu + ((c.u >> 16) & 1u);
  return (u16)(r >> 16);
}
__device__ __forceinline__ float bf2f(u16 u){
  union { unsigned int u; float f; } c; c.u = ((unsigned int)u) << 16;
  return c.f;
}

// weight conversions (per layer, each call)
__global__ void wconv_in2_kernel(const float* __restrict__ w, u16* __restrict__ o){
  int idx = blockIdx.x*256 + threadIdx.x;       // N1PAD*DMODEL total
  int n = idx / DMODEL, k = idx % DMODEL;
  o[idx] = (n < DPROJ) ? f2bf(w[(size_t)n*DMODEL + k]) : (u16)0;
}
__global__ void wconv_out_kernel(const float* __restrict__ w, u16* __restrict__ o){
  int idx = blockIdx.x*256 + threadIdx.x;       // 384*768 total
  o[idx] = f2bf(w[idx]);
}

// xbf = bf16( LN(in)*lnw + lnb ), one wave per row.
// FUSE_PE=1 (layer 0): in = emb, adds positional encoding inline and also
// writes x (residual stream).
template<int FUSE_PE>
__global__ void __launch_bounds__(256) ln_bf_kernel(const float* __restrict__ in,
    const float* __restrict__ lnw, const float* __restrict__ lnb,
    u16* __restrict__ xbf, float* __restrict__ xout){
  int wave = threadIdx.x >> 6, lane = threadIdx.x & 63;
  int m = blockIdx.x*4 + wave;
  const float* row = in + (size_t)m*DMODEL;
  float v[6], s=0.f, s2=0.f;
  #pragma unroll
  for (int j=0;j<6;j++){
    int d = lane + 64*j;
    float val = row[d];
    if (FUSE_PE){
      int l = m & (SEQ-1);
      int i = d >> 1;
      float div = expf((float)(2*i) * (-9.210340371976184f/384.f));
      float arg = (float)l * div;
      val += (d & 1) ? cosf(arg) : sinf(arg);
    }
    v[j] = val; s += val; s2 += val*val;
  }
  #pragma unroll
  for (int off=32;off;off>>=1){ s += __shfl_xor(s,off,64); s2 += __shfl_xor(s2,off,64); }
  float m1 = s * (1.f/384.f);
  float var = s2 * (1.f/384.f) - m1*m1;
  float rstd = rsqrtf(var + 1e-5f);
  u16* orow = xbf + (size_t)m*DMODEL;
  float* xrow = FUSE_PE ? (xout + (size_t)m*DMODEL) : nullptr;
  #pragma unroll
  for (int j=0;j<6;j++){
    int d = lane + 64*j;
    if (FUSE_PE) xrow[d] = v[j];
    orow[d] = f2bf((v[j]-m1)*rstd*lnw[d] + lnb[d]);
  }
}

// IN-PROJ bf16 MFMA GEMM: 128x256 tile, 8 waves (512 thr), wave-tile 64x64
// (acc[4][4] = 64 VGPR, no spill). BK=32, 2-buffer, counted vmcnt(3) +
// dual barrier (R11 schedule). Half the blocks of the 128x128 version ->
// each A-panel fetched by 7 blocks not 14; 24 waves/CU.
__global__ void __launch_bounds__(512) gemm_in_bf16(
    const u16* __restrict__ A, const u16* __restrict__ W,
    u16* __restrict__ zo, u16* __restrict__ xbcro, float* __restrict__ dto,
    const float* __restrict__ dt_bias)
{
  __shared__ __align__(16) u16 As[2*128*32];   // 16 KB
  __shared__ __align__(16) u16 Bs[2*256*32];   // 32 KB
  const int K = DMODEL;
  const int tid = threadIdx.x;
  const int l = tid & 63;
  const int w = tid >> 6;             // 0..7
  const int wm = w >> 2, wn = w & 3;  // 2 x 4 wave grid

  int bx = blockIdx.x, by = blockIdx.y;
  {
    const int nwg = gridDim.x * gridDim.y;   // 7*256 = 1792, %8==0
    if ((nwg & 7) == 0){
      const int id  = by * gridDim.x + bx;
      const int nid = (id & 7) * (nwg >> 3) + (id >> 3);
      bx = nid % gridDim.x;
      by = nid / gridDim.x;
    }
  }
  const int m0 = by * 128, n0 = bx * 256;

  f32x4 acc[4][4];
  #pragma unroll
  for (int i=0;i<4;i++)
    #pragma unroll
    for (int j=0;j<4;j++)
      acc[i][j] = (f32x4){0.f,0.f,0.f,0.f};

  // staging: wave w covers 16 rows per instruction (64 lanes x 16B = 1 KB)
  const u16* Abase = A + (size_t)(m0 + w*16 + (l>>2))*K + (l&3)*8;
  const u16* Wb0   = W + (size_t)(n0 +       w*16 + (l>>2))*K + (l&3)*8;
  const u16* Wb1   = W + (size_t)(n0 + 128 + w*16 + (l>>2))*K + (l&3)*8;

  auto stage = [&](int buf, int k0){
    __builtin_amdgcn_global_load_lds((const ASG void*)(Abase + k0),
                                     (ASL void*)(&As[buf*4096 + w*512]), 16, 0, 0);
    __builtin_amdgcn_global_load_lds((const ASG void*)(Wb0 + k0),
                                     (ASL void*)(&Bs[buf*8192 + w*512]), 16, 0, 0);
    __builtin_amdgcn_global_load_lds((const ASG void*)(Wb1 + k0),
                                     (ASL void*)(&Bs[buf*8192 + 4096 + w*512]), 16, 0, 0);
  };

  const int nt = K >> 5;              // 12
  stage(0, 0);
  const int rr = l & 15;
  const int ko = (l >> 4) << 3;
  for (int t = 0; t < nt; t++){
    if (t + 1 < nt){
      stage((t+1)&1, (t+1)<<5);
      asm volatile("s_waitcnt vmcnt(3)" ::: "memory");   // own stage(t) landed
    } else {
      asm volatile("s_waitcnt vmcnt(0)" ::: "memory");
    }
    __builtin_amdgcn_s_barrier();
    __builtin_amdgcn_sched_barrier(0);
    const u16* Ac = &As[(t&1)*4096];
    const u16* Bc = &Bs[(t&1)*8192];
    bf16x8 af[4], bfv[4];
    #pragma unroll
    for (int f=0; f<4; f++){
      af[f]  = *(const bf16x8*)&Ac[(wm*64 + f*16 + rr)*32 + ko];
      bfv[f] = *(const bf16x8*)&Bc[(wn*64 + f*16 + rr)*32 + ko];
    }
    #pragma unroll
    for (int fi=0; fi<4; fi++)
      #pragma unroll
      for (int fj=0; fj<4; fj++)
        acc[fi][fj] = __builtin_amdgcn_mfma_f32_16x16x32_bf16(af[fi], bfv[fj], acc[fi][fj], 0, 0, 0);
    asm volatile("s_waitcnt lgkmcnt(0)" ::: "memory");   // LDS reads done
    __builtin_amdgcn_sched_barrier(0);
    __builtin_amdgcn_s_barrier();                        // safe to overwrite buf
  }

  const int cg = l & 15;
  const int rb = (l >> 4) * 4;
  #pragma unroll
  for (int fi=0; fi<4; fi++){
    #pragma unroll
    for (int r=0; r<4; r++){
      const int m = m0 + wm*64 + fi*16 + rb + r;
      #pragma unroll
      for (int fj=0; fj<4; fj++){
        const int n = n0 + wn*64 + fj*16 + cg;
        float v = acc[fi][fj][r];
        if (n < DINNER)              zo[(size_t)m*DINNER + n] = f2bf(v);
        else if (n < DINNER+CONVDIM) xbcro[(size_t)m*CONVDIM + n - DINNER] = f2bf(v);
        else if (n < DPROJ)          dto[(size_t)m*NHEADS + n - (DINNER+CONVDIM)] =
                                        softplusf(v + dt_bias[n - (DINNER+CONVDIM)]);
      }
    }
  }
}

// OUT-PROJ bf16 MFMA GEMM: R11's 128x128 tile, BK=32, counted vmcnt(4) +
// dual barrier. C += residual (f32).
__global__ void __launch_bounds__(256) gemm_out_bf16(
    const u16* __restrict__ A, const u16* __restrict__ W, float* __restrict__ xres)
{
  __shared__ __align__(16) u16 As[2*128*32];
  __shared__ __align__(16) u16 Bs[2*128*32];
  const int K = DINNER;
  const int tid = threadIdx.x;
  const int l = tid & 63;
  const int w = tid >> 6;
  const int wm = w >> 1, wn = w & 1;

  int bx = blockIdx.x, by = blockIdx.y;
  {
    const int nwg = gridDim.x * gridDim.y;
    if ((nwg & 7) == 0){
      const int id  = by * gridDim.x + bx;
      const int nid = (id & 7) * (nwg >> 3) + (id >> 3);
      bx = nid % gridDim.x;
      by = nid / gridDim.x;
    }
  }
  const int m0 = by * 128, n0 = bx * 128;

  f32x4 acc[4][4];
  #pragma unroll
  for (int i=0;i<4;i++)
    #pragma unroll
    for (int j=0;j<4;j++)
      acc[i][j] = (f32x4){0.f,0.f,0.f,0.f};

  const int grow = tid >> 2;
  const int gcol = (tid & 3) * 8;
  const u16* Abase = A + (size_t)(m0 + grow)*K + gcol;
  const u16* Wbase = W + (size_t)(n0 + grow)*K + gcol;
  const int lb = w*512;

  auto stage = [&](int buf, int k0){
    #pragma unroll
    for (int it=0; it<2; it++){
      __builtin_amdgcn_global_load_lds((const ASG void*)(Abase + (size_t)it*64*K + k0),
                                       (ASL void*)(&As[buf*4096 + it*2048 + lb]), 16, 0, 0);
      __builtin_amdgcn_global_load_lds((const ASG void*)(Wbase + (size_t)it*64*K + k0),
                                       (ASL void*)(&Bs[buf*4096 + it*2048 + lb]), 16, 0, 0);
    }
  };

  const int nt = K >> 5;                // 24
  stage(0, 0);
  const int rr = l & 15;
  const int ko = (l >> 4) << 3;
  for (int t = 0; t < nt; t++){
    if (t + 1 < nt){
      stage((t+1)&1, (t+1)<<5);
      asm volatile("s_waitcnt vmcnt(4)" ::: "memory");
    } else {
      asm volatile("s_waitcnt vmcnt(0)" ::: "memory");
    }
    __builtin_amdgcn_s_barrier();
    __builtin_amdgcn_sched_barrier(0);
    const u16* Ac = &As[(t&1)*4096];
    const u16* Bc = &Bs[(t&1)*4096];
    bf16x8 af[4], bfv[4];
    #pragma unroll
    for (int f=0; f<4; f++){
      af[f]  = *(const bf16x8*)&Ac[(wm*64 + f*16 + rr)*32 + ko];
      bfv[f] = *(const bf16x8*)&Bc[(wn*64 + f*16 + rr)*32 + ko];
    }
    #pragma unroll
    for (int fi=0; fi<4; fi++)
      #pragma unroll
      for (int fj=0; fj<4; fj++)
        acc[fi][fj] = __builtin_amdgcn_mfma_f32_16x16x32_bf16(af[fi], bfv[fj], acc[fi][fj], 0, 0, 0);
    asm volatile("s_waitcnt lgkmcnt(0)" ::: "memory");
    __builtin_amdgcn_sched_barrier(0);
    __builtin_amdgcn_s_barrier();
  }

  const int cg = l & 15;
  const int rb = (l >> 4) * 4;
  #pragma unroll
  for (int fi=0; fi<4; fi++){
    #pragma unroll
    for (int r=0; r<4; r++){
      const int m = m0 + wm*64 + fi*16 + rb + r;
      #pragma unroll
      for (int fj=0; fj<4; fj++){
        const int n = n0 + wn*64 + fj*16 + cg;
        xres[(size_t)m*DMODEL + n] += acc[fi][fj][r];
      }
    }
  }
}

// conv+SiLU for the shared B/C channels only (computed ONCE, not per head).
__global__ void __launch_bounds__(256) conv_bc_kernel(
    const u16* __restrict__ xbcr, const float* __restrict__ cw,
    const float* __restrict__ cb, u16* __restrict__ xbcc)
{
  int idx = blockIdx.x*256 + threadIdx.x;      // Mc*16 total
  int row = idx >> 4;
  int c8  = (idx & 15) * 8;                    // 0..120 within B|C block
  int lq  = row & (SEQ-1);
  const u16* src = xbcr + (size_t)row*CONVDIM + DINNER + c8;
  bf16x8 tap[4];
  #pragma unroll
  for (int k=0;k<4;k++){
    int d = k - 3;
    if (lq + d >= 0) tap[k] = *(const bf16x8*)(src + (long)d*CONVDIM);
    else             tap[k] = (bf16x8){0,0,0,0,0,0,0,0};
  }
  bf16x8 o;
  #pragma unroll
  for (int j=0;j<8;j++){
    const float4 wv = *(const float4*)&cw[(DINNER + c8 + j)*4];
    float a = cb[DINNER + c8 + j]
            + bf2f((u16)tap[0][j])*wv.x + bf2f((u16)tap[1][j])*wv.y
            + bf2f((u16)tap[2][j])*wv.z + bf2f((u16)tap[3][j])*wv.w;
    o[j] = (short)f2bf(siluf(a));
  }
  *(bf16x8*)&xbcc[(size_t)row*128 + c8] = o;
}

// SSD (Mamba2 matrix form), one block per (batch, head).
// LDS XOR-swizzled (byte ^= (row&7)<<4). B/C pre-conv'd (xbcc); X conv fused.
__global__ void __launch_bounds__(256) ssd_kernel(
  const u16* __restrict__ xbcr, const u16* __restrict__ xbcc,
  const float* __restrict__ dtb,
  const float* __restrict__ cw, const float* __restrict__ cb,
  const float* __restrict__ A_log, const float* __restrict__ Dp,
  u16* __restrict__ y)
{
  const int b = blockIdx.x, h = blockIdx.y;
  const int tid = threadIdx.x;
  const int l = tid & 63;
  const int w = tid >> 6;
  const float A  = -__expf(A_log[h]);
  const float Dh = Dp[h];

  __shared__ __align__(16) u16 cbm[128*128];   // C[128][64]@0 | B[128][64]@16K; M[128][128] reuses
  __shared__ __align__(16) u16 XtS[64*128];    // Xt[p][s]
  __shared__ float cum[128];
  __shared__ float dts[128];
  char* Cb = (char*)cbm;
  char* Bb = (char*)cbm + 16384;
  char* Mb = (char*)cbm;
  char* Xb = (char*)XtS;

  const u16* xrow  = xbcr + (size_t)b*SEQ*CONVDIM;
  const u16* ccrow = xbcc + (size_t)b*SEQ*128;

  // wave 0: dt loads + shuffle-based inclusive cumsum of dt*A (no barriers)
  if (w == 0){
    float a0 = dtb[((size_t)b*SEQ + 2*l)*NHEADS + h];
    float a1 = dtb[((size_t)b*SEQ + 2*l+1)*NHEADS + h];
    float ps = (a0 + a1) * A;
    #pragma unroll
    for (int off=1; off<64; off<<=1){
      float v = __shfl_up(ps, off, 64);
      if (l >= off) ps += v;
    }
    float excl = ps - (a0 + a1)*A;
    cum[2*l]   = excl + a0*A;
    cum[2*l+1] = ps;
    dts[2*l]   = a0;
    dts[2*l+1] = a1;
  }

  // stage conv'd B/C: plain b128 copy into swizzled LDS
  {
    const int row0 = tid >> 4;          // 0..15
    const int colc = (tid & 15) * 8;    // 0..120
    #pragma unroll
    for (int it=0; it<8; it++){
      const int r = row0 + 16*it;
      bf16x8 v = *(const bf16x8*)&ccrow[(size_t)r*128 + colc];
      if (colc < 64) *(bf16x8*)(Bb + ((r*128 + 2*colc)      ^ ((r&7)<<4))) = v;
      else           *(bf16x8*)(Cb + ((r*128 + 2*(colc-64)) ^ ((r&7)<<4))) = v;
    }
  }

  // stage X transposed with rolling conv: wave w owns s in [32w,32w+32), lane = p
  {
    const int cx = h*HEADDIM + l;
    const float4 cwx = *(const float4*)&cw[cx*4];
    const float cbx = cb[cx];
    const int sb = 32*w;
    float p3=0.f, p2=0.f, p1=0.f;
    if (w > 0){
      p3 = bf2f(xrow[(size_t)(sb-3)*CONVDIM + cx]);
      p2 = bf2f(xrow[(size_t)(sb-2)*CONVDIM + cx]);
      p1 = bf2f(xrow[(size_t)(sb-1)*CONVDIM + cx]);
    }
    #pragma unroll
    for (int it=0; it<16; it++){
      const int s = sb + 2*it;
      const float r0 = bf2f(xrow[(size_t)s*CONVDIM + cx]);
      const float r1 = bf2f(xrow[(size_t)(s+1)*CONVDIM + cx]);
      const float v0 = siluf(cbx + p3*cwx.x + p2*cwx.y + p1*cwx.z + r0*cwx.w);
      const float v1 = siluf(cbx + p2*cwx.x + p1*cwx.y + r0*cwx.z + r1*cwx.w);
      const u32 pk = (u32)f2bf(v0) | ((u32)f2bf(v1) << 16);
      *(u32*)(Xb + ((l*256 + 2*s) ^ ((l&7)<<4))) = pk;
      p3 = p1; p2 = r0; p1 = r1;
    }
  }
  __syncthreads();

  // ---- G = C · B^T : wave w -> rows [32w,32w+32) x 128 cols ----
  const int t0 = w*32;
  const int rr = l & 15;
  const int kg = (l >> 4) << 3;
  f32x4 g[2][8];
  #pragma unroll
  for (int i=0;i<2;i++)
    #pragma unroll
    for (int j=0;j<8;j++)
      g[i][j] = (f32x4){0.f,0.f,0.f,0.f};
  #pragma unroll
  for (int k0=0; k0<64; k0+=32){
    const int ko = k0 + kg;
    bf16x8 af[2], bfv[8];
    #pragma unroll
    for (int fi=0; fi<2; fi++){
      const int r = t0 + 16*fi + rr;
      af[fi] = *(const bf16x8*)(Cb + ((r*128 + 2*ko) ^ ((r&7)<<4)));
    }
    #pragma unroll
    for (int fj=0; fj<8; fj++){
      const int r = 16*fj + rr;
      bfv[fj] = *(const bf16x8*)(Bb + ((r*128 + 2*ko) ^ ((r&7)<<4)));
    }
    #pragma unroll
    for (int fi=0; fi<2; fi++)
      #pragma unroll
      for (int fj=0; fj<8; fj++)
        g[fi][fj] = __builtin_amdgcn_mfma_f32_16x16x32_bf16(af[fi], bfv[fj], g[fi][fj], 0, 0, 0);
  }
  __syncthreads();   // C/B reads done; M may overwrite

  // ---- M[t,s] = mask * exp(cum[t]-cum[s]) * dt[s] * G ----
  {
    const int rowg = (l >> 4) * 4;
    const int colg = l & 15;
    #pragma unroll
    for (int fi=0; fi<2; fi++){
      #pragma unroll
      for (int fj=0; fj<8; fj++){
        const int s = 16*fj + colg;
        const float cs = cum[s];
        const float ds = dts[s];
        #pragma unroll
        for (int r=0; r<4; r++){
          const int t = t0 + 16*fi + rowg + r;
          float m = 0.f;
          if (t >= s) m = __expf(cum[t] - cs) * ds * g[fi][fj][r];
          *(u16*)(Mb + ((t*256 + 2*s) ^ ((t&7)<<4))) = f2bf(m);
        }
      }
    }
  }
  __syncthreads();

  // ---- Y = M · Xt : rows [32w,32w+32) x 64, K = 128 ----
  f32x4 acc[2][4];
  #pragma unroll
  for (int i=0;i<2;i++)
    #pragma unroll
    for (int j=0;j<4;j++)
      acc[i][j] = (f32x4){0.f,0.f,0.f,0.f};
  #pragma unroll
  for (int k0=0; k0<128; k0+=32){
    const int ko = k0 + kg;
    bf16x8 af[2], bfv[4];
    #pragma unroll
    for (int fi=0; fi<2; fi++){
      const int r = t0 + 16*fi + rr;
      af[fi] = *(const bf16x8*)(Mb + ((r*256 + 2*ko) ^ ((r&7)<<4)));
    }
    #pragma unroll
    for (int fj=0; fj<4; fj++){
      const int r = 16*fj + rr;
      bfv[fj] = *(const bf16x8*)(Xb + ((r*256 + 2*ko) ^ ((r&7)<<4)));
    }
    #pragma unroll
    for (int fi=0; fi<2; fi++)
      #pragma unroll
      for (int fj=0; fj<4; fj++)
        acc[fi][fj] = __builtin_amdgcn_mfma_f32_16x16x32_bf16(af[fi], bfv[fj], acc[fi][fj], 0, 0, 0);
  }

  // ---- epilogue: y = Y + D*x (conv'd x from swizzled XtS) ----
  {
    const int rowg = (l >> 4) * 4;
    const int colg = l & 15;
    u16* yb = y + (size_t)b*SEQ*DINNER + h*HEADDIM;
    #pragma unroll
    for (int fi=0; fi<2; fi++){
      #pragma unroll
      for (int r=0; r<4; r++){
        const int t = t0 + 16*fi + rowg + r;
        #pragma unroll
        for (int fj=0; fj<4; fj++){
          const int p = 16*fj + colg;
          const float xval = bf2f(*(const u16*)(Xb + ((p*256 + 2*t) ^ ((p&7)<<4))));
          yb[(size_t)t*DINNER + p] = f2bf(acc[fi][fj][r] + Dh*xval);
        }
      }
    }
  }
}

// g = y * silu(z); g *= rsqrt(mean(g^2)+eps) * norm_w  (bf16 in-place in y)
// 192 threads/row, 4 bf16 per thread via uint2 (8B) loads/stores.
__global__ void __launch_bounds__(192) gate_rms_bf_kernel(const u16* __restrict__ z,
    const float* __restrict__ normw, u16* __restrict__ y){
  const int m = blockIdx.x, tid = threadIdx.x;
  const uint2 zz = *(const uint2*)(z + (size_t)m*DINNER + tid*4);
  const uint2 yy = *(const uint2*)(y + (size_t)m*DINNER + tid*4);
  float gv[4];
  gv[0] = bf2f((u16)(yy.x & 0xffff)) * siluf(bf2f((u16)(zz.x & 0xffff)));
  gv[1] = bf2f((u16)(yy.x >> 16))    * siluf(bf2f((u16)(zz.x >> 16)));
  gv[2] = bf2f((u16)(yy.y & 0xffff)) * siluf(bf2f((u16)(zz.y & 0xffff)));
  gv[3] = bf2f((u16)(yy.y >> 16))    * siluf(bf2f((u16)(zz.y >> 16)));
  float ss = gv[0]*gv[0] + gv[1]*gv[1] + gv[2]*gv[2] + gv[3]*gv[3];
  #pragma unroll
  for (int off=32;off;off>>=1) ss += __shfl_xor(ss,off,64);
  __shared__ float red[3];
  if ((tid&63)==0) red[tid>>6] = ss;
  __syncthreads();
  const float rms = rsqrtf((red[0]+red[1]+red[2])*(1.f/768.f) + 1e-5f);
  const float4 nw = *(const float4*)(normw + tid*4);
  u32 o0 = (u32)f2bf(gv[0]*rms*nw.x) | ((u32)f2bf(gv[1]*rms*nw.y) << 16);
  u32 o1 = (u32)f2bf(gv[2]*rms*nw.z) | ((u32)f2bf(gv[3]*rms*nw.w) << 16);
  *(uint2*)(y + (size_t)m*DINNER + tid*4) = make_uint2(o0, o1);
}

// final LN on last timestep + 60x384 projection (f32)
__global__ void __launch_bounds__(64) final_kernel(const float* __restrict__ x,
  const float* __restrict__ onw, const float* __restrict__ onb,
  const float* __restrict__ pw, const float* __restrict__ pb, float* __restrict__ out)
{
  int b = blockIdx.x;
  int lane = threadIdx.x;
  const float* row = x + ((size_t)b*SEQ + (SEQ-1))*DMODEL;
  float s=0.f, s2=0.f;
  float v[6];
  #pragma unroll
  for (int j=0;j<6;j++){ v[j] = row[lane + 64*j]; s += v[j]; s2 += v[j]*v[j]; }
  #pragma unroll
  for (int off=32;off;off>>=1){ s += __shfl_xor(s,off,64); s2 += __shfl_xor(s2,off,64); }
  float m1 = s*(1.f/384.f);
  float var = s2*(1.f/384.f) - m1*m1;
  float rstd = rsqrtf(var + 1e-5f);
  __shared__ float xn[384];
  #pragma unroll
  for (int j=0;j<6;j++){
    int d = lane + 64*j;
    xn[d] = (v[j]-m1)*rstd*onw[d] + onb[d];
  }
  __syncthreads();
  if (lane < OUTDIM){
    const float* wrow = pw + lane*DMODEL;
    float acc = pb[lane];
    #pragma unroll 4
    for (int d=0; d<DMODEL; d+=4){
      float4 xv = *(const float4*)&xn[d];
      float4 wv = *(const float4*)&wrow[d];
      acc += xv.x*wv.x + xv.y*wv.y + xv.z*wv.z + xv.w*wv.w;
    }
    out[b*OUTDIM + lane] = acc;
  }
}

extern "C" void kernel_launch(void* const* d_in, const int* in_sizes, int n_in,
                              void* d_out, int out_size, void* d_ws, size_t ws_size,
                              hipStream_t stream){
  const float* emb        = (const float*)d_in[0];
  const float* in_proj_w  = (const float*)d_in[1];
  const float* conv_w     = (const float*)d_in[2];
  const float* conv_b     = (const float*)d_in[3];
  const float* dt_bias    = (const float*)d_in[4];
  const float* A_log      = (const float*)d_in[5];
  const float* Dp         = (const float*)d_in[6];
  const float* mnw        = (const float*)d_in[7];
  const float* out_proj_w = (const float*)d_in[8];
  const float* ln_w       = (const float*)d_in[9];
  const float* ln_b       = (const float*)d_in[10];
  const float* onw        = (const float*)d_in[11];
  const float* onb        = (const float*)d_in[12];
  const float* pw         = (const float*)d_in[13];
  const float* pb         = (const float*)d_in[14];
  float* out = (float*)d_out;

  // ---- adaptive workspace ----
  const size_t XB    = (size_t)MTOT*DMODEL*4;
  const size_t XBFB  = (size_t)MTOT*DMODEL*2;
  const size_t WINB  = (size_t)N1PAD*DMODEL*2;
  const size_t WOUTB = (size_t)DMODEL*DINNER*2;
  const size_t fixed = XB + XBFB + WINB + WOUTB;
  int CB = 256;
  while (CB > 1 && fixed + (size_t)CB*SEQ*5168ull > ws_size) CB >>= 1;
  const int Mc = CB*SEQ;
  const int nchunks = BATCH / CB;

  char* p = (char*)d_ws;
  float* x      = (float*)p;  p += XB;
  u16*   xbf    = (u16*)p;    p += XBFB;
  u16*   wbfin  = (u16*)p;    p += WINB;
  u16*   wbfout = (u16*)p;    p += WOUTB;
  u16*   z      = (u16*)p;    p += (size_t)Mc*DINNER*2;
  u16*   xbcr   = (u16*)p;    p += (size_t)Mc*CONVDIM*2;
  u16*   xbcc   = (u16*)p;    p += (size_t)Mc*128*2;
  float* dt     = (float*)p;  p += (size_t)Mc*NHEADS*4;
  u16*   y      = (u16*)p;

  for (int i=0;i<2;i++){
    wconv_in2_kernel<<<N1PAD*DMODEL/256,256,0,stream>>>(in_proj_w + (size_t)i*DPROJ*DMODEL, wbfin);
    wconv_out_kernel<<<DMODEL*DINNER/256,256,0,stream>>>(out_proj_w + (size_t)i*DMODEL*DINNER, wbfout);
    if (i == 0)
      ln_bf_kernel<1><<<MTOT/4,256,0,stream>>>(emb, ln_w, ln_b, xbf, x);
    else
      ln_bf_kernel<0><<<MTOT/4,256,0,stream>>>(x, ln_w + (size_t)i*DMODEL, ln_b + (size_t)i*DMODEL, xbf, nullptr);
    for (int c=0;c<nchunks;c++){
      const u16* ac = xbf + (size_t)c*Mc*DMODEL;
      float*     xc = x   + (size_t)c*Mc*DMODEL;
      dim3 g1(N1PAD/256, Mc/128);
      gemm_in_bf16<<<g1,512,0,stream>>>(ac, wbfin, z, xbcr, dt, dt_bias + (size_t)i*NHEADS);
      conv_bc_kernel<<<Mc/16,256,0,stream>>>(xbcr, conv_w + (size_t)i*CONVDIM*4,
                                             conv_b + (size_t)i*CONVDIM, xbcc);
      dim3 gs(CB, NHEADS);
      ssd_kernel<<<gs,256,0,stream>>>(xbcr, xbcc, dt,
          conv_w + (size_t)i*CONVDIM*4, conv_b + (size_t)i*CONVDIM,
          A_log + (size_t)i*NHEADS, Dp + (size_t)i*NHEADS, y);
      gate_rms_bf_kernel<<<Mc,192,0,stream>>>(z, mnw + (size_t)i*DINNER, y);
      dim3 g2(DMODEL/128, Mc/128);
      gemm_out_bf16<<<g2,256,0,stream>>>(y, wbfout, xc);
    }
  }
  final_kernel<<<BATCH,64,0,stream>>>(x, onw, onb, pw, pb, out);
}

// Round 19
// 500.769 us; speedup vs baseline: 2.8830x; 1.0494x over previous
//
#include <hip/hip_runtime.h>
#include <math.h>

#define BATCH   256
#define SEQ     128
#define DMODEL  384
#define DSTATE  64
#define DINNER  768
#define NHEADS  12
#define HEADDIM 64
#define CONVDIM 896
#define DPROJ   1676
#define N1PAD   1792
#define OUTDIM  60
#define MTOT    (BATCH*SEQ)   // 32768

typedef unsigned short u16;
typedef unsigned int   u32;
typedef short bf16x8 __attribute__((ext_vector_type(8)));
typedef float f32x4 __attribute__((ext_vector_type(4)));

#define ASG __attribute__((address_space(1)))
#define ASL __attribute__((address_space(3)))

__device__ __forceinline__ float siluf(float x){ return __fdividef(x, 1.f + __expf(-x)); }
__device__ __forceinline__ float softplusf(float x){ return fmaxf(x,0.f) + log1pf(expf(-fabsf(x))); }
__device__ __forceinline__ u16 f2bf(float x){
  union { float f; unsigned int u; } c; c.f = x;
  unsigned int r = c.u + 0x7FFFu + ((c.u >> 16) & 1u);
  return (u16)(r >> 16);
}
__device__ __forceinline__ float bf2f(u16 u){
  union { unsigned int u; float f; } c; c.u = ((unsigned int)u) << 16;
  return c.f;
}

// weight conversions (per layer, each call)
__global__ void wconv_in2_kernel(const float* __restrict__ w, u16* __restrict__ o){
  int idx = blockIdx.x*256 + threadIdx.x;       // N1PAD*DMODEL total
  int n = idx / DMODEL, k = idx % DMODEL;
  o[idx] = (n < DPROJ) ? f2bf(w[(size_t)n*DMODEL + k]) : (u16)0;
}
__global__ void wconv_out_kernel(const float* __restrict__ w, u16* __restrict__ o){
  int idx = blockIdx.x*256 + threadIdx.x;       // 384*768 total
  o[idx] = f2bf(w[idx]);
}

// xbf = bf16( LN(in)*lnw + lnb ), one wave per row.
// FUSE_PE=1 (layer 0): in = emb, adds positional encoding inline and also
// writes x (residual stream).
template<int FUSE_PE>
__global__ void __launch_bounds__(256) ln_bf_kernel(const float* __restrict__ in,
    const float* __restrict__ lnw, const float* __restrict__ lnb,
    u16* __restrict__ xbf, float* __restrict__ xout){
  int wave = threadIdx.x >> 6, lane = threadIdx.x & 63;
  int m = blockIdx.x*4 + wave;
  const float* row = in + (size_t)m*DMODEL;
  float v[6], s=0.f, s2=0.f;
  #pragma unroll
  for (int j=0;j<6;j++){
    int d = lane + 64*j;
    float val = row[d];
    if (FUSE_PE){
      int l = m & (SEQ-1);
      int i = d >> 1;
      float div = expf((float)(2*i) * (-9.210340371976184f/384.f));
      float arg = (float)l * div;
      val += (d & 1) ? cosf(arg) : sinf(arg);
    }
    v[j] = val; s += val; s2 += val*val;
  }
  #pragma unroll
  for (int off=32;off;off>>=1){ s += __shfl_xor(s,off,64); s2 += __shfl_xor(s2,off,64); }
  float m1 = s * (1.f/384.f);
  float var = s2 * (1.f/384.f) - m1*m1;
  float rstd = rsqrtf(var + 1e-5f);
  u16* orow = xbf + (size_t)m*DMODEL;
  float* xrow = FUSE_PE ? (xout + (size_t)m*DMODEL) : nullptr;
  #pragma unroll
  for (int j=0;j<6;j++){
    int d = lane + 64*j;
    if (FUSE_PE) xrow[d] = v[j];
    orow[d] = f2bf((v[j]-m1)*rstd*lnw[d] + lnb[d]);
  }
}

// IN-PROJ bf16 MFMA GEMM: 128x256 tile, 8 waves (512 thr), wave-tile 64x64.
// BK=32, 2-buffer, counted vmcnt(3) + dual barrier. (R18, measured best)
__global__ void __launch_bounds__(512) gemm_in_bf16(
    const u16* __restrict__ A, const u16* __restrict__ W,
    u16* __restrict__ zo, u16* __restrict__ xbcro, float* __restrict__ dto,
    const float* __restrict__ dt_bias)
{
  __shared__ __align__(16) u16 As[2*128*32];   // 16 KB
  __shared__ __align__(16) u16 Bs[2*256*32];   // 32 KB
  const int K = DMODEL;
  const int tid = threadIdx.x;
  const int l = tid & 63;
  const int w = tid >> 6;             // 0..7
  const int wm = w >> 2, wn = w & 3;  // 2 x 4 wave grid

  int bx = blockIdx.x, by = blockIdx.y;
  {
    const int nwg = gridDim.x * gridDim.y;   // 7*256 = 1792, %8==0
    if ((nwg & 7) == 0){
      const int id  = by * gridDim.x + bx;
      const int nid = (id & 7) * (nwg >> 3) + (id >> 3);
      bx = nid % gridDim.x;
      by = nid / gridDim.x;
    }
  }
  const int m0 = by * 128, n0 = bx * 256;

  f32x4 acc[4][4];
  #pragma unroll
  for (int i=0;i<4;i++)
    #pragma unroll
    for (int j=0;j<4;j++)
      acc[i][j] = (f32x4){0.f,0.f,0.f,0.f};

  const u16* Abase = A + (size_t)(m0 + w*16 + (l>>2))*K + (l&3)*8;
  const u16* Wb0   = W + (size_t)(n0 +       w*16 + (l>>2))*K + (l&3)*8;
  const u16* Wb1   = W + (size_t)(n0 + 128 + w*16 + (l>>2))*K + (l&3)*8;

  auto stage = [&](int buf, int k0){
    __builtin_amdgcn_global_load_lds((const ASG void*)(Abase + k0),
                                     (ASL void*)(&As[buf*4096 + w*512]), 16, 0, 0);
    __builtin_amdgcn_global_load_lds((const ASG void*)(Wb0 + k0),
                                     (ASL void*)(&Bs[buf*8192 + w*512]), 16, 0, 0);
    __builtin_amdgcn_global_load_lds((const ASG void*)(Wb1 + k0),
                                     (ASL void*)(&Bs[buf*8192 + 4096 + w*512]), 16, 0, 0);
  };

  const int nt = K >> 5;              // 12
  stage(0, 0);
  const int rr = l & 15;
  const int ko = (l >> 4) << 3;
  for (int t = 0; t < nt; t++){
    if (t + 1 < nt){
      stage((t+1)&1, (t+1)<<5);
      asm volatile("s_waitcnt vmcnt(3)" ::: "memory");   // own stage(t) landed
    } else {
      asm volatile("s_waitcnt vmcnt(0)" ::: "memory");
    }
    __builtin_amdgcn_s_barrier();
    __builtin_amdgcn_sched_barrier(0);
    const u16* Ac = &As[(t&1)*4096];
    const u16* Bc = &Bs[(t&1)*8192];
    bf16x8 af[4], bfv[4];
    #pragma unroll
    for (int f=0; f<4; f++){
      af[f]  = *(const bf16x8*)&Ac[(wm*64 + f*16 + rr)*32 + ko];
      bfv[f] = *(const bf16x8*)&Bc[(wn*64 + f*16 + rr)*32 + ko];
    }
    #pragma unroll
    for (int fi=0; fi<4; fi++)
      #pragma unroll
      for (int fj=0; fj<4; fj++)
        acc[fi][fj] = __builtin_amdgcn_mfma_f32_16x16x32_bf16(af[fi], bfv[fj], acc[fi][fj], 0, 0, 0);
    asm volatile("s_waitcnt lgkmcnt(0)" ::: "memory");   // LDS reads done
    __builtin_amdgcn_sched_barrier(0);
    __builtin_amdgcn_s_barrier();                        // safe to overwrite buf
  }

  const int cg = l & 15;
  const int rb = (l >> 4) * 4;
  #pragma unroll
  for (int fi=0; fi<4; fi++){
    #pragma unroll
    for (int r=0; r<4; r++){
      const int m = m0 + wm*64 + fi*16 + rb + r;
      #pragma unroll
      for (int fj=0; fj<4; fj++){
        const int n = n0 + wn*64 + fj*16 + cg;
        float v = acc[fi][fj][r];
        if (n < DINNER)              zo[(size_t)m*DINNER + n] = f2bf(v);
        else if (n < DINNER+CONVDIM) xbcro[(size_t)m*CONVDIM + n - DINNER] = f2bf(v);
        else if (n < DPROJ)          dto[(size_t)m*NHEADS + n - (DINNER+CONVDIM)] =
                                        softplusf(v + dt_bias[n - (DINNER+CONVDIM)]);
      }
    }
  }
}

// OUT-PROJ bf16 MFMA GEMM: 256x128 tile, 8 waves (512 thr), wave-tile 64x64
// (4x2 wave grid). BK=32, 2-buffer, counted vmcnt(3) + dual barrier.
// C += residual (f32). Same per-wave resources as gemm_in (proven no-spill).
__global__ void __launch_bounds__(512) gemm_out_bf16(
    const u16* __restrict__ A, const u16* __restrict__ W, float* __restrict__ xres)
{
  __shared__ __align__(16) u16 As[2*256*32];   // 32 KB
  __shared__ __align__(16) u16 Bs[2*128*32];   // 16 KB
  const int K = DINNER;
  const int tid = threadIdx.x;
  const int l = tid & 63;
  const int w = tid >> 6;             // 0..7
  const int wm = w >> 1, wn = w & 1;  // 4 x 2 wave grid

  int bx = blockIdx.x, by = blockIdx.y;
  {
    const int nwg = gridDim.x * gridDim.y;   // 3*128 = 384, %8==0
    if ((nwg & 7) == 0){
      const int id  = by * gridDim.x + bx;
      const int nid = (id & 7) * (nwg >> 3) + (id >> 3);
      bx = nid % gridDim.x;
      by = nid / gridDim.x;
    }
  }
  const int m0 = by * 256, n0 = bx * 128;

  f32x4 acc[4][4];
  #pragma unroll
  for (int i=0;i<4;i++)
    #pragma unroll
    for (int j=0;j<4;j++)
      acc[i][j] = (f32x4){0.f,0.f,0.f,0.f};

  // staging: A 256 rows -> 2 instrs/wave (rows w*32, w*32+16); B 128 rows -> 1 instr/wave
  const u16* Abase = A + (size_t)(m0 + w*32 + (l>>2))*K + (l&3)*8;
  const u16* Wbase = W + (size_t)(n0 + w*16 + (l>>2))*K + (l&3)*8;

  auto stage = [&](int buf, int k0){
    __builtin_amdgcn_global_load_lds((const ASG void*)(Abase + k0),
                                     (ASL void*)(&As[buf*8192 + w*1024]), 16, 0, 0);
    __builtin_amdgcn_global_load_lds((const ASG void*)(Abase + (size_t)16*K + k0),
                                     (ASL void*)(&As[buf*8192 + w*1024 + 512]), 16, 0, 0);
    __builtin_amdgcn_global_load_lds((const ASG void*)(Wbase + k0),
                                     (ASL void*)(&Bs[buf*4096 + w*512]), 16, 0, 0);
  };

  const int nt = K >> 5;                // 24
  stage(0, 0);
  const int rr = l & 15;
  const int ko = (l >> 4) << 3;
  for (int t = 0; t < nt; t++){
    if (t + 1 < nt){
      stage((t+1)&1, (t+1)<<5);
      asm volatile("s_waitcnt vmcnt(3)" ::: "memory");
    } else {
      asm volatile("s_waitcnt vmcnt(0)" ::: "memory");
    }
    __builtin_amdgcn_s_barrier();
    __builtin_amdgcn_sched_barrier(0);
    const u16* Ac = &As[(t&1)*8192];
    const u16* Bc = &Bs[(t&1)*4096];
    bf16x8 af[4], bfv[4];
    #pragma unroll
    for (int f=0; f<4; f++){
      af[f]  = *(const bf16x8*)&Ac[(wm*64 + f*16 + rr)*32 + ko];
      bfv[f] = *(const bf16x8*)&Bc[(wn*64 + f*16 + rr)*32 + ko];
    }
    #pragma unroll
    for (int fi=0; fi<4; fi++)
      #pragma unroll
      for (int fj=0; fj<4; fj++)
        acc[fi][fj] = __builtin_amdgcn_mfma_f32_16x16x32_bf16(af[fi], bfv[fj], acc[fi][fj], 0, 0, 0);
    asm volatile("s_waitcnt lgkmcnt(0)" ::: "memory");
    __builtin_amdgcn_sched_barrier(0);
    __builtin_amdgcn_s_barrier();
  }

  const int cg = l & 15;
  const int rb = (l >> 4) * 4;
  #pragma unroll
  for (int fi=0; fi<4; fi++){
    #pragma unroll
    for (int r=0; r<4; r++){
      const int m = m0 + wm*64 + fi*16 + rb + r;
      #pragma unroll
      for (int fj=0; fj<4; fj++){
        const int n = n0 + wn*64 + fj*16 + cg;
        xres[(size_t)m*DMODEL + n] += acc[fi][fj][r];
      }
    }
  }
}

// conv+SiLU for the shared B/C channels only (computed ONCE, not per head).
__global__ void __launch_bounds__(256) conv_bc_kernel(
    const u16* __restrict__ xbcr, const float* __restrict__ cw,
    const float* __restrict__ cb, u16* __restrict__ xbcc)
{
  int idx = blockIdx.x*256 + threadIdx.x;      // Mc*16 total
  int row = idx >> 4;
  int c8  = (idx & 15) * 8;                    // 0..120 within B|C block
  int lq  = row & (SEQ-1);
  const u16* src = xbcr + (size_t)row*CONVDIM + DINNER + c8;
  bf16x8 tap[4];
  #pragma unroll
  for (int k=0;k<4;k++){
    int d = k - 3;
    if (lq + d >= 0) tap[k] = *(const bf16x8*)(src + (long)d*CONVDIM);
    else             tap[k] = (bf16x8){0,0,0,0,0,0,0,0};
  }
  bf16x8 o;
  #pragma unroll
  for (int j=0;j<8;j++){
    const float4 wv = *(const float4*)&cw[(DINNER + c8 + j)*4];
    float a = cb[DINNER + c8 + j]
            + bf2f((u16)tap[0][j])*wv.x + bf2f((u16)tap[1][j])*wv.y
            + bf2f((u16)tap[2][j])*wv.z + bf2f((u16)tap[3][j])*wv.w;
    o[j] = (short)f2bf(siluf(a));
  }
  *(bf16x8*)&xbcc[(size_t)row*128 + c8] = o;
}

// SSD (Mamba2 matrix form), one block per (batch, head).
// LDS XOR-swizzled (byte ^= (row&7)<<4). B/C pre-conv'd (xbcc); X conv fused.
__global__ void __launch_bounds__(256) ssd_kernel(
  const u16* __restrict__ xbcr, const u16* __restrict__ xbcc,
  const float* __restrict__ dtb,
  const float* __restrict__ cw, const float* __restrict__ cb,
  const float* __restrict__ A_log, const float* __restrict__ Dp,
  u16* __restrict__ y)
{
  const int b = blockIdx.x, h = blockIdx.y;
  const int tid = threadIdx.x;
  const int l = tid & 63;
  const int w = tid >> 6;
  const float A  = -__expf(A_log[h]);
  const float Dh = Dp[h];

  __shared__ __align__(16) u16 cbm[128*128];   // C[128][64]@0 | B[128][64]@16K; M[128][128] reuses
  __shared__ __align__(16) u16 XtS[64*128];    // Xt[p][s]
  __shared__ float cum[128];
  __shared__ float dts[128];
  char* Cb = (char*)cbm;
  char* Bb = (char*)cbm + 16384;
  char* Mb = (char*)cbm;
  char* Xb = (char*)XtS;

  const u16* xrow  = xbcr + (size_t)b*SEQ*CONVDIM;
  const u16* ccrow = xbcc + (size_t)b*SEQ*128;

  // wave 0: dt loads + shuffle-based inclusive cumsum of dt*A (no barriers)
  if (w == 0){
    float a0 = dtb[((size_t)b*SEQ + 2*l)*NHEADS + h];
    float a1 = dtb[((size_t)b*SEQ + 2*l+1)*NHEADS + h];
    float ps = (a0 + a1) * A;
    #pragma unroll
    for (int off=1; off<64; off<<=1){
      float v = __shfl_up(ps, off, 64);
      if (l >= off) ps += v;
    }
    float excl = ps - (a0 + a1)*A;
    cum[2*l]   = excl + a0*A;
    cum[2*l+1] = ps;
    dts[2*l]   = a0;
    dts[2*l+1] = a1;
  }

  // stage conv'd B/C: plain b128 copy into swizzled LDS
  {
    const int row0 = tid >> 4;          // 0..15
    const int colc = (tid & 15) * 8;    // 0..120
    #pragma unroll
    for (int it=0; it<8; it++){
      const int r = row0 + 16*it;
      bf16x8 v = *(const bf16x8*)&ccrow[(size_t)r*128 + colc];
      if (colc < 64) *(bf16x8*)(Bb + ((r*128 + 2*colc)      ^ ((r&7)<<4))) = v;
      else           *(bf16x8*)(Cb + ((r*128 + 2*(colc-64)) ^ ((r&7)<<4))) = v;
    }
  }

  // stage X transposed with rolling conv: wave w owns s in [32w,32w+32), lane = p
  {
    const int cx = h*HEADDIM + l;
    const float4 cwx = *(const float4*)&cw[cx*4];
    const float cbx = cb[cx];
    const int sb = 32*w;
    float p3=0.f, p2=0.f, p1=0.f;
    if (w > 0){
      p3 = bf2f(xrow[(size_t)(sb-3)*CONVDIM + cx]);
      p2 = bf2f(xrow[(size_t)(sb-2)*CONVDIM + cx]);
      p1 = bf2f(xrow[(size_t)(sb-1)*CONVDIM + cx]);
    }
    #pragma unroll
    for (int it=0; it<16; it++){
      const int s = sb + 2*it;
      const float r0 = bf2f(xrow[(size_t)s*CONVDIM + cx]);
      const float r1 = bf2f(xrow[(size_t)(s+1)*CONVDIM + cx]);
      const float v0 = siluf(cbx + p3*cwx.x + p2*cwx.y + p1*cwx.z + r0*cwx.w);
      const float v1 = siluf(cbx + p2*cwx.x + p1*cwx.y + r0*cwx.z + r1*cwx.w);
      const u32 pk = (u32)f2bf(v0) | ((u32)f2bf(v1) << 16);
      *(u32*)(Xb + ((l*256 + 2*s) ^ ((l&7)<<4))) = pk;
      p3 = p1; p2 = r0; p1 = r1;
    }
  }
  __syncthreads();

  // ---- G = C · B^T : wave w -> rows [32w,32w+32) x 128 cols ----
  const int t0 = w*32;
  const int rr = l & 15;
  const int kg = (l >> 4) << 3;
  f32x4 g[2][8];
  #pragma unroll
  for (int i=0;i<2;i++)
    #pragma unroll
    for (int j=0;j<8;j++)
      g[i][j] = (f32x4){0.f,0.f,0.f,0.f};
  #pragma unroll
  for (int k0=0; k0<64; k0+=32){
    const int ko = k0 + kg;
    bf16x8 af[2], bfv[8];
    #pragma unroll
    for (int fi=0; fi<2; fi++){
      const int r = t0 + 16*fi + rr;
      af[fi] = *(const bf16x8*)(Cb + ((r*128 + 2*ko) ^ ((r&7)<<4)));
    }
    #pragma unroll
    for (int fj=0; fj<8; fj++){
      const int r = 16*fj + rr;
      bfv[fj] = *(const bf16x8*)(Bb + ((r*128 + 2*ko) ^ ((r&7)<<4)));
    }
    #pragma unroll
    for (int fi=0; fi<2; fi++)
      #pragma unroll
      for (int fj=0; fj<8; fj++)
        g[fi][fj] = __builtin_amdgcn_mfma_f32_16x16x32_bf16(af[fi], bfv[fj], g[fi][fj], 0, 0, 0);
  }
  __syncthreads();   // C/B reads done; M may overwrite

  // ---- M[t,s] = mask * exp(cum[t]-cum[s]) * dt[s] * G ----
  {
    const int rowg = (l >> 4) * 4;
    const int colg = l & 15;
    #pragma unroll
    for (int fi=0; fi<2; fi++){
      #pragma unroll
      for (int fj=0; fj<8; fj++){
        const int s = 16*fj + colg;
        const float cs = cum[s];
        const float ds = dts[s];
        #pragma unroll
        for (int r=0; r<4; r++){
          const int t = t0 + 16*fi + rowg + r;
          float m = 0.f;
          if (t >= s) m = __expf(cum[t] - cs) * ds * g[fi][fj][r];
          *(u16*)(Mb + ((t*256 + 2*s) ^ ((t&7)<<4))) = f2bf(m);
        }
      }
    }
  }
  __syncthreads();

  // ---- Y = M · Xt : rows [32w,32w+32) x 64, K = 128 ----
  f32x4 acc[2][4];
  #pragma unroll
  for (int i=0;i<2;i++)
    #pragma unroll
    for (int j=0;j<4;j++)
      acc[i][j] = (f32x4){0.f,0.f,0.f,0.f};
  #pragma unroll
  for (int k0=0; k0<128; k0+=32){
    const int ko = k0 + kg;
    bf16x8 af[2], bfv[4];
    #pragma unroll
    for (int fi=0; fi<2; fi++){
      const int r = t0 + 16*fi + rr;
      af[fi] = *(const bf16x8*)(Mb + ((r*256 + 2*ko) ^ ((r&7)<<4)));
    }
    #pragma unroll
    for (int fj=0; fj<4; fj++){
      const int r = 16*fj + rr;
      bfv[fj] = *(const bf16x8*)(Xb + ((r*256 + 2*ko) ^ ((r&7)<<4)));
    }
    #pragma unroll
    for (int fi=0; fi<2; fi++)
      #pragma unroll
      for (int fj=0; fj<4; fj++)
        acc[fi][fj] = __builtin_amdgcn_mfma_f32_16x16x32_bf16(af[fi], bfv[fj], acc[fi][fj], 0, 0, 0);
  }

  // ---- epilogue: y = Y + D*x (conv'd x from swizzled XtS) ----
  {
    const int rowg = (l >> 4) * 4;
    const int colg = l & 15;
    u16* yb = y + (size_t)b*SEQ*DINNER + h*HEADDIM;
    #pragma unroll
    for (int fi=0; fi<2; fi++){
      #pragma unroll
      for (int r=0; r<4; r++){
        const int t = t0 + 16*fi + rowg + r;
        #pragma unroll
        for (int fj=0; fj<4; fj++){
          const int p = 16*fj + colg;
          const float xval = bf2f(*(const u16*)(Xb + ((p*256 + 2*t) ^ ((p&7)<<4))));
          yb[(size_t)t*DINNER + p] = f2bf(acc[fi][fj][r] + Dh*xval);
        }
      }
    }
  }
}

// g = y * silu(z); g *= rsqrt(mean(g^2)+eps) * norm_w  (bf16 in-place in y)
// 192 threads/row, 4 bf16 per thread via uint2 (8B) loads/stores.
__global__ void __launch_bounds__(192) gate_rms_bf_kernel(const u16* __restrict__ z,
    const float* __restrict__ normw, u16* __restrict__ y){
  const int m = blockIdx.x, tid = threadIdx.x;
  const uint2 zz = *(const uint2*)(z + (size_t)m*DINNER + tid*4);
  const uint2 yy = *(const uint2*)(y + (size_t)m*DINNER + tid*4);
  float gv[4];
  gv[0] = bf2f((u16)(yy.x & 0xffff)) * siluf(bf2f((u16)(zz.x & 0xffff)));
  gv[1] = bf2f((u16)(yy.x >> 16))    * siluf(bf2f((u16)(zz.x >> 16)));
  gv[2] = bf2f((u16)(yy.y & 0xffff)) * siluf(bf2f((u16)(zz.y & 0xffff)));
  gv[3] = bf2f((u16)(yy.y >> 16))    * siluf(bf2f((u16)(zz.y >> 16)));
  float ss = gv[0]*gv[0] + gv[1]*gv[1] + gv[2]*gv[2] + gv[3]*gv[3];
  #pragma unroll
  for (int off=32;off;off>>=1) ss += __shfl_xor(ss,off,64);
  __shared__ float red[3];
  if ((tid&63)==0) red[tid>>6] = ss;
  __syncthreads();
  const float rms = rsqrtf((red[0]+red[1]+red[2])*(1.f/768.f) + 1e-5f);
  const float4 nw = *(const float4*)(normw + tid*4);
  u32 o0 = (u32)f2bf(gv[0]*rms*nw.x) | ((u32)f2bf(gv[1]*rms*nw.y) << 16);
  u32 o1 = (u32)f2bf(gv[2]*rms*nw.z) | ((u32)f2bf(gv[3]*rms*nw.w) << 16);
  *(uint2*)(y + (size_t)m*DINNER + tid*4) = make_uint2(o0, o1);
}

// final LN on last timestep + 60x384 projection (f32)
__global__ void __launch_bounds__(64) final_kernel(const float* __restrict__ x,
  const float* __restrict__ onw, const float* __restrict__ onb,
  const float* __restrict__ pw, const float* __restrict__ pb, float* __restrict__ out)
{
  int b = blockIdx.x;
  int lane = threadIdx.x;
  const float* row = x + ((size_t)b*SEQ + (SEQ-1))*DMODEL;
  float s=0.f, s2=0.f;
  float v[6];
  #pragma unroll
  for (int j=0;j<6;j++){ v[j] = row[lane + 64*j]; s += v[j]; s2 += v[j]*v[j]; }
  #pragma unroll
  for (int off=32;off;off>>=1){ s += __shfl_xor(s,off,64); s2 += __shfl_xor(s2,off,64); }
  float m1 = s*(1.f/384.f);
  float var = s2*(1.f/384.f) - m1*m1;
  float rstd = rsqrtf(var + 1e-5f);
  __shared__ float xn[384];
  #pragma unroll
  for (int j=0;j<6;j++){
    int d = lane + 64*j;
    xn[d] = (v[j]-m1)*rstd*onw[d] + onb[d];
  }
  __syncthreads();
  if (lane < OUTDIM){
    const float* wrow = pw + lane*DMODEL;
    float acc = pb[lane];
    #pragma unroll 4
    for (int d=0; d<DMODEL; d+=4){
      float4 xv = *(const float4*)&xn[d];
      float4 wv = *(const float4*)&wrow[d];
      acc += xv.x*wv.x + xv.y*wv.y + xv.z*wv.z + xv.w*wv.w;
    }
    out[b*OUTDIM + lane] = acc;
  }
}

extern "C" void kernel_launch(void* const* d_in, const int* in_sizes, int n_in,
                              void* d_out, int out_size, void* d_ws, size_t ws_size,
                              hipStream_t stream){
  const float* emb        = (const float*)d_in[0];
  const float* in_proj_w  = (const float*)d_in[1];
  const float* conv_w     = (const float*)d_in[2];
  const float* conv_b     = (const float*)d_in[3];
  const float* dt_bias    = (const float*)d_in[4];
  const float* A_log      = (const float*)d_in[5];
  const float* Dp         = (const float*)d_in[6];
  const float* mnw        = (const float*)d_in[7];
  const float* out_proj_w = (const float*)d_in[8];
  const float* ln_w       = (const float*)d_in[9];
  const float* ln_b       = (const float*)d_in[10];
  const float* onw        = (const float*)d_in[11];
  const float* onb        = (const float*)d_in[12];
  const float* pw         = (const float*)d_in[13];
  const float* pb         = (const float*)d_in[14];
  float* out = (float*)d_out;

  // ---- adaptive workspace ----
  const size_t XB    = (size_t)MTOT*DMODEL*4;
  const size_t XBFB  = (size_t)MTOT*DMODEL*2;
  const size_t WINB  = (size_t)N1PAD*DMODEL*2;
  const size_t WOUTB = (size_t)DMODEL*DINNER*2;
  const size_t fixed = XB + XBFB + WINB + WOUTB;
  int CB = 256;
  while (CB > 1 && fixed + (size_t)CB*SEQ*5168ull > ws_size) CB >>= 1;
  const int Mc = CB*SEQ;
  const int nchunks = BATCH / CB;

  char* p = (char*)d_ws;
  float* x      = (float*)p;  p += XB;
  u16*   xbf    = (u16*)p;    p += XBFB;
  u16*   wbfin  = (u16*)p;    p += WINB;
  u16*   wbfout = (u16*)p;    p += WOUTB;
  u16*   z      = (u16*)p;    p += (size_t)Mc*DINNER*2;
  u16*   xbcr   = (u16*)p;    p += (size_t)Mc*CONVDIM*2;
  u16*   xbcc   = (u16*)p;    p += (size_t)Mc*128*2;
  float* dt     = (float*)p;  p += (size_t)Mc*NHEADS*4;
  u16*   y      = (u16*)p;

  for (int i=0;i<2;i++){
    wconv_in2_kernel<<<N1PAD*DMODEL/256,256,0,stream>>>(in_proj_w + (size_t)i*DPROJ*DMODEL, wbfin);
    wconv_out_kernel<<<DMODEL*DINNER/256,256,0,stream>>>(out_proj_w + (size_t)i*DMODEL*DINNER, wbfout);
    if (i == 0)
      ln_bf_kernel<1><<<MTOT/4,256,0,stream>>>(emb, ln_w, ln_b, xbf, x);
    else
      ln_bf_kernel<0><<<MTOT/4,256,0,stream>>>(x, ln_w + (size_t)i*DMODEL, ln_b + (size_t)i*DMODEL, xbf, nullptr);
    for (int c=0;c<nchunks;c++){
      const u16* ac = xbf + (size_t)c*Mc*DMODEL;
      float*     xc = x   + (size_t)c*Mc*DMODEL;
      dim3 g1(N1PAD/256, Mc/128);
      gemm_in_bf16<<<g1,512,0,stream>>>(ac, wbfin, z, xbcr, dt, dt_bias + (size_t)i*NHEADS);
      conv_bc_kernel<<<Mc/16,256,0,stream>>>(xbcr, conv_w + (size_t)i*CONVDIM*4,
                                             conv_b + (size_t)i*CONVDIM, xbcc);
      dim3 gs(CB, NHEADS);
      ssd_kernel<<<gs,256,0,stream>>>(xbcr, xbcc, dt,
          conv_w + (size_t)i*CONVDIM*4, conv_b + (size_t)i*CONVDIM,
          A_log + (size_t)i*NHEADS, Dp + (size_t)i*NHEADS, y);
      gate_rms_bf_kernel<<<Mc,192,0,stream>>>(z, mnw + (size_t)i*DINNER, y);
      dim3 g2(DMODEL/128, Mc/256);
      gemm_out_bf16<<<g2,512,0,stream>>>(y, wbfout, xc);
    }
  }
  final_kernel<<<BATCH,64,0,stream>>>(x, onw, onb, pw, pb, out);
}